// Round 9
// baseline (1162.786 us; speedup 1.0000x reference)
//
#include <hip/hip_runtime.h>
#include <hip/hip_bf16.h>
#include <math.h>

// Problem constants
#define D_DIM 128
#define M_CODES 2048
#define BN_TOT 65536           // B*N = 16*4096
#define OUT_LOSS 8388608       // flat offset of loss
#define OUT_PERP 8388609       // flat offset of perp
#define OUT_IDX 8388610        // flat offset of indices
#define MARGIN 2e-3f           // covers ref fp32 noise (~1.6e-5) + bf16-split err

#define QB 128                 // queries per argmin block (4 q-groups x 2 slices)
#define EPI_BLOCKS 8192

// ws byte offsets
#define WS_L2K 0               // float l2k[2048]              (8 KB)
#define WS_PB 8192             // bf16 packed codebook, 1 MB: 64 pchunks x 16 KB
#define WS_IDX 1056768         // int best_idx[65536]          (256 KB)
#define WS_PART 1318912        // float loss_part[8192]        (32 KB)
#define WS_CNT 1351680         // int counts[2048]             (8 KB)
#define WS_DONE 1359872        // int done_counter (epilogue last-block)

typedef __bf16 bf16x8 __attribute__((ext_vector_type(8)));
typedef float f32x4 __attribute__((ext_vector_type(4)));

// async 16B/lane global->LDS copy: LDS dest is wave-uniform base + lane*16
#define GLOAD_LDS16(g, l)                                         \
  __builtin_amdgcn_global_load_lds(                               \
      (const __attribute__((address_space(1))) void*)(g),         \
      (__attribute__((address_space(3))) void*)(l), 16, 0, 0)

#define MFMA16(a, b, c) __builtin_amdgcn_mfma_f32_16x16x32_bf16((a), (b), (c), 0, 0, 0)

// ---------------------------------------------------------------------------
// prep: fuses (a) emulated-np ||k||^2 (terms rounded fp32, fp64 sum, round
// back -> matches ref within ~1 ulp), (b) codebook prepack, (c) counts /
// done-counter zeroing. Grid 256x256.
//
// Pack layout (UNCHANGED, verified v3..v8): pchunk p (32 codes) occupies
// bytes [p*16384, (p+1)*16384). granule g = p*16 + cid (1 KB):
//   cid in [0,8):  hi part, ks = cid>>1, wc = cid&1
//   cid in [8,16): lo part, k2 = cid-8, ks = k2>>1, wc = k2&1
// lane l (col=l&15, quad=l>>4), elem j in [0,8):
//   value = w[p*32 + wc*16 + col][ks*32 + quad*8 + j]
// ---------------------------------------------------------------------------
__global__ __launch_bounds__(256) void prep_kernel(const float* __restrict__ w,
                                                   float* __restrict__ l2k,
                                                   __bf16* __restrict__ pb,
                                                   int* __restrict__ counts,
                                                   int* __restrict__ done) {
  int gid = blockIdx.x * 256 + threadIdx.x;

  if (gid < M_CODES) {
    const float4* p = (const float4*)(w + (size_t)gid * D_DIM);
    double s = 0.0;
#pragma unroll
    for (int j = 0; j < 32; ++j) {
      float4 v = p[j];
      s += (double)(v.x * v.x);
      s += (double)(v.y * v.y);
      s += (double)(v.z * v.z);
      s += (double)(v.w * v.w);
    }
    l2k[gid] = (float)s;
    counts[gid] = 0;
    if (gid == 0) *done = 0;
  }

  // pack: gid is a lane-granule id, 65536 total
  int lane = gid & 63;
  int g = gid >> 6;                          // granule 0..1023
  int cid = g & 15;
  int p = g >> 4;
  int k2 = cid & 7;
  int ks = k2 >> 1;
  int wc = k2 & 1;
  int code = p * 32 + wc * 16 + (lane & 15);
  int koff = ks * 32 + (lane >> 4) * 8;
  const float* src = w + (size_t)code * D_DIM + koff;
  float4 u = *(const float4*)src;
  float4 v = *(const float4*)(src + 4);
  float f[8] = {u.x, u.y, u.z, u.w, v.x, v.y, v.z, v.w};
  bf16x8 o;
#pragma unroll
  for (int j = 0; j < 8; ++j) {
    __bf16 hh = (__bf16)f[j];
    o[j] = (cid < 8) ? hh : (__bf16)(f[j] - (float)hh);
  }
  *(bf16x8*)(pb + (size_t)g * 512 + lane * 8) = o;
}

// max-form merge: (b,s)=best/second-best of acc (=sim-0.5*l2k; argmax),
// first-index tie-break
__device__ __forceinline__ void merge_bs(float& b, float& s, int& i,
                                         float ob, float os, int oi) {
  if (ob > b) {
    s = fmaxf(b, os);
    b = ob;
    i = oi;
  } else if (ob < b) {
    s = fmaxf(s, ob);
  } else {           // tie: gap 0 -> flagged -> in-block fixup resolves exactly
    s = b;
    if (oi < i) i = oi;
  }
}

// ---------------------------------------------------------------------------
// MFMA argmin v9. v8 (104us, MfmaUtil 43%) confirmed the rounds model
// (QB=128, 8-wave blocks, 1 round) but launch_bounds(512,4)'s 128-reg cap
// spilled ~5 dwords/thread (WRITE_SIZE 5.4MB). v9:
//  - drops the DO_KS register prefetch (proven null in v6.1) -> frees ~16
//    VGPRs -> no spill. Per-acc MFMA order unchanged -> bit-identical.
//  - folds the fp64 fixup INTO the block tail: a block's flagged queries
//    (gap < MARGIN) depend only on this block; the whole block rescans
//    each flagged query vs all 2048 codes in fp64, byte-identical numerics
//    to the old fixup_kernel. Saves one kernel launch + flagged workspace.
// ---------------------------------------------------------------------------
__global__ __launch_bounds__(512, 4) void argmin_mfma(
    const float* __restrict__ x, const __bf16* __restrict__ pb,
    const float* __restrict__ l2k, const float* __restrict__ w,
    int* __restrict__ best_idx) {
  __shared__ __align__(16) unsigned char ldsB[2 * 32768];
  __shared__ float redB[8][32];
  __shared__ float redS[8][32];
  __shared__ int redI[8][32];
  __shared__ int flcnt;
  __shared__ int flist[QB];
  __shared__ float l2q_sh;

  const int tid = threadIdx.x;
  const int wv = tid >> 6;        // wave 0..7
  const int lane = tid & 63;
  const int col = lane & 15;      // MFMA n-index / A m-index
  const int quad = lane >> 4;     // 0..3
  const int wc = wv & 1;          // code-slice within pchunk
  const int wq = wv >> 1;         // query group 0..3 (32 q each)
  const int q0 = blockIdx.x * QB;

  if (tid == 0) flcnt = 0;

  // ---- A fragments for this wave's 32 queries, fp32 -> hi/lo bf16, in regs
  bf16x8 ah[2][4], al[2][4];
#pragma unroll
  for (int mt = 0; mt < 2; ++mt) {
#pragma unroll
    for (int ks = 0; ks < 4; ++ks) {
      const float* xr =
          x + (size_t)(q0 + wq * 32 + 16 * mt + col) * D_DIM + 32 * ks + 8 * quad;
      float4 u = *(const float4*)xr;
      float4 v = *(const float4*)(xr + 4);
      float f[8] = {u.x, u.y, u.z, u.w, v.x, v.y, v.z, v.w};
      bf16x8 h, l;
#pragma unroll
      for (int j = 0; j < 8; ++j) {
        __bf16 hh = (__bf16)f[j];
        h[j] = hh;
        l[j] = (__bf16)(f[j] - (float)hh);
      }
      ah[mt][ks] = h;
      al[mt][ks] = l;
    }
  }

  // per-lane running argmax state over acc = sim - 0.5*l2k
  float m1[2][4], m2[2][4];
  int bp[2][4];                   // best pchunk id (full index rebuilt later)
#pragma unroll
  for (int mt = 0; mt < 2; ++mt)
#pragma unroll
    for (int r = 0; r < 4; ++r) {
      m1[mt][r] = -3.4e38f;
      m2[mt][r] = -3.4e38f;
      bp[mt][r] = 0;
    }

  const int ldsw = wc * 1024 + lane * 16;
  const float* l2p = l2k + wc * 16 + col;

  // stage chunk ch (64 codes = 32 KB = pchunks 2ch, 2ch+1); 4 granules/wave.
  // db MUST include the per-wave dest offset (+wv*4096) — v6 lesson.
  auto stage = [&](int ch, unsigned char* db) {
    const char* s = (const char*)pb + (size_t)ch * 32768 + wv * 4096 + lane * 16;
#pragma unroll
    for (int i = 0; i < 4; ++i) GLOAD_LDS16(s + i * 1024, db + i * 1024);
  };

  stage(0, ldsB + wv * 4096);     // per-wave dest offset!
  float l2a = l2p[0];
  float l2b = l2p[32];
  __syncthreads();   // drains vmcnt -> stage(0) complete

#pragma unroll 1
  for (int ch = 0; ch < 32; ++ch) {
    const int buf = ch & 1;
    if (ch < 31) stage(ch + 1, ldsB + (buf ^ 1) * 32768 + wv * 4096);
    float l2na = 0.f, l2nb = 0.f;
    if (ch < 31) {                          // l2 for chunk ch+1 (latency hidden)
      l2na = l2p[(2 * ch + 2) * 32];
      l2nb = l2p[(2 * ch + 3) * 32];
    }

    // ---- compute chunk ch: 48 MFMA (plain per-ks loads; prefetch was null)
    const unsigned char* rb = ldsB + buf * 32768 + ldsw;
    float ia = -0.5f * l2a, ib = -0.5f * l2b;
    f32x4 a00 = (f32x4){ia, ia, ia, ia};
    f32x4 a10 = (f32x4){ia, ia, ia, ia};
    f32x4 a01 = (f32x4){ib, ib, ib, ib};
    f32x4 a11 = (f32x4){ib, ib, ib, ib};

#pragma unroll
    for (int ks = 0; ks < 4; ++ks) {
      bf16x8 bh0 = *(const bf16x8*)(rb + ks * 2048);
      bf16x8 bl0 = *(const bf16x8*)(rb + 8192 + ks * 2048);
      bf16x8 bh1 = *(const bf16x8*)(rb + 16384 + ks * 2048);
      bf16x8 bl1 = *(const bf16x8*)(rb + 24576 + ks * 2048);
      a00 = MFMA16(al[0][ks], bh0, a00);
      a10 = MFMA16(al[1][ks], bh0, a10);
      a01 = MFMA16(al[0][ks], bh1, a01);
      a11 = MFMA16(al[1][ks], bh1, a11);
      a00 = MFMA16(ah[0][ks], bl0, a00);
      a10 = MFMA16(ah[1][ks], bl0, a10);
      a01 = MFMA16(ah[0][ks], bl1, a01);
      a11 = MFMA16(ah[1][ks], bl1, a11);
      a00 = MFMA16(ah[0][ks], bh0, a00);
      a10 = MFMA16(ah[1][ks], bh0, a10);
      a01 = MFMA16(ah[0][ks], bh1, a01);
      a11 = MFMA16(ah[1][ks], bh1, a11);
    }

    // fold (argmax, branchless second-max, pchunk-id index).
    // candidates ascend over (ch, nt) -> strict > keeps first index.
#pragma unroll
    for (int mt = 0; mt < 2; ++mt) {
#pragma unroll
      for (int r = 0; r < 4; ++r) {
        float dd = (mt == 0) ? a00[r] : a10[r];
        bool gt = dd > m1[mt][r];
        m2[mt][r] = fmaxf(m2[mt][r], fminf(m1[mt][r], dd));
        bp[mt][r] = gt ? (ch * 2 + 0) : bp[mt][r];
        m1[mt][r] = fmaxf(m1[mt][r], dd);
      }
    }
#pragma unroll
    for (int mt = 0; mt < 2; ++mt) {
#pragma unroll
      for (int r = 0; r < 4; ++r) {
        float dd = (mt == 0) ? a01[r] : a11[r];
        bool gt = dd > m1[mt][r];
        m2[mt][r] = fmaxf(m2[mt][r], fminf(m1[mt][r], dd));
        bp[mt][r] = gt ? (ch * 2 + 1) : bp[mt][r];
        m1[mt][r] = fmaxf(m1[mt][r], dd);
      }
    }

    l2a = l2na;
    l2b = l2nb;
    __syncthreads();              // next buf staged + this buf reads done
  }

  // ---- Cross-lane reduction: 16 cols per quad-row ----
#pragma unroll
  for (int mt = 0; mt < 2; ++mt) {
#pragma unroll
    for (int r = 0; r < 4; ++r) {
      float b = m1[mt][r], s = m2[mt][r];
      int i = bp[mt][r] * 32 + wc * 16 + col;   // full code index
#pragma unroll
      for (int m = 1; m < 16; m <<= 1) {
        float ob = __shfl_xor(b, m);
        float os = __shfl_xor(s, m);
        int oi = __shfl_xor(i, m);
        merge_bs(b, s, i, ob, os, oi);
      }
      if (col == 0) {
        int qloc = 16 * mt + 4 * quad + r;
        redB[wv][qloc] = b;
        redS[wv][qloc] = s;
        redI[wv][qloc] = i;
      }
    }
  }
  __syncthreads();

  // ---- Final merge across the 2 code-slice waves of each query group ----
  if (tid < QB) {
    int wg = tid >> 5;            // query group 0..3
    int ql = tid & 31;
    float b = -3.4e38f, s = -3.4e38f;
    int i = 0x7fffffff;
    merge_bs(b, s, i, redB[wg * 2 + 0][ql], redS[wg * 2 + 0][ql], redI[wg * 2 + 0][ql]);
    merge_bs(b, s, i, redB[wg * 2 + 1][ql], redS[wg * 2 + 1][ql], redI[wg * 2 + 1][ql]);
    best_idx[q0 + tid] = i;
    // dist gap = 2*(b - s) on acc scale
    if (2.0f * (b - s) < MARGIN) {
      int pos = atomicAdd(&flcnt, 1);
      flist[pos] = tid;           // local query id
    }
  }
  __syncthreads();

  // ---- In-block fixup tail: exact fp64 rescan for flagged queries.
  // Emulates the reference fp32 computation exactly (same as the old
  // fixup_kernel): dist = fl32(fl32(l2q+l2k[c]) - fl32(2*fl32(q.k))),
  // q.k in fp64 rounded once; first-index tie-break. ldsB is dead ->
  // reuse for qs / reduction arrays.
  const int nf = flcnt;
  if (nf > 0) {
    float* qs = (float*)ldsB;                    // 128 floats
    float* redD = (float*)(ldsB + 2048);         // 512 floats
    int* redIx = (int*)(ldsB + 4096);            // 512 ints
    for (int f = 0; f < nf; ++f) {
      int q = q0 + flist[f];
      if (tid < D_DIM) qs[tid] = x[(size_t)q * D_DIM + tid];
      __syncthreads();
      if (tid == 0) {
        double s = 0.0;
        for (int d = 0; d < D_DIM; ++d) {
          float t = qs[d] * qs[d];
          s += (double)t;
        }
        l2q_sh = (float)s;
      }
      __syncthreads();
      const float l2q = l2q_sh;
      float bd = 3.4e38f;
      int bi = 0x7fffffff;
      for (int c = tid; c < M_CODES; c += 512) {
        const float4* wr = (const float4*)(w + (size_t)c * D_DIM);
        double s = 0.0;
#pragma unroll
        for (int j = 0; j < 32; ++j) {
          float4 v = wr[j];
          s = fma((double)qs[j * 4 + 0], (double)v.x, s);
          s = fma((double)qs[j * 4 + 1], (double)v.y, s);
          s = fma((double)qs[j * 4 + 2], (double)v.z, s);
          s = fma((double)qs[j * 4 + 3], (double)v.w, s);
        }
        float simf = (float)s;
        float S = l2q + l2k[c];
        float T = 2.0f * simf;
        float dist = S - T;
        if (dist < bd) { bd = dist; bi = c; }
      }
      redD[tid] = bd;
      redIx[tid] = bi;
      __syncthreads();
      for (int off = 256; off; off >>= 1) {
        if (tid < off) {
          float od = redD[tid + off];
          int oi = redIx[tid + off];
          if (od < redD[tid] || (od == redD[tid] && oi < redIx[tid])) {
            redD[tid] = od;
            redIx[tid] = oi;
          }
        }
        __syncthreads();
      }
      if (tid == 0) best_idx[q] = redIx[0];
      __syncthreads();
    }
  }
}

// ---------------------------------------------------------------------------
// Gather + straight-through output + loss partials + histogram + indices out
// + last-block finalize (loss mean + perplexity). Device-scope fence +
// atomic done-counter publishes part[]/counts[] to the last block (G16).
// ---------------------------------------------------------------------------
__global__ __launch_bounds__(256) void epilogue_kernel(const float* __restrict__ x,
                                                       const float* __restrict__ w,
                                                       const int* __restrict__ best_idx,
                                                       float* __restrict__ out,
                                                       float* __restrict__ part,
                                                       int* __restrict__ counts,
                                                       int* __restrict__ done) {
  int gid = blockIdx.x * 256 + threadIdx.x;  // float4 id, 2,097,152 total
  int q = gid >> 5;
  int d4 = gid & 31;
  int idx = best_idx[q];
  float4 xv = ((const float4*)x)[gid];
  float4 wv = ((const float4*)w)[(size_t)idx * 32 + d4];
  float4 o;
  float t0 = wv.x - xv.x; o.x = xv.x + t0; float e0 = o.x - xv.x;
  float t1 = wv.y - xv.y; o.y = xv.y + t1; float e1 = o.y - xv.y;
  float t2 = wv.z - xv.z; o.z = xv.z + t2; float e2 = o.z - xv.z;
  float t3 = wv.w - xv.w; o.w = xv.w + t3; float e3 = o.w - xv.w;
  float ls = e0 * e0 + e1 * e1 + e2 * e2 + e3 * e3;
  ((float4*)out)[gid] = o;

  for (int off = 32; off; off >>= 1) ls += __shfl_down(ls, off);
  __shared__ float red[4];
  if ((threadIdx.x & 63) == 0) red[threadIdx.x >> 6] = ls;
  __syncthreads();
  if (threadIdx.x == 0) part[blockIdx.x] = red[0] + red[1] + red[2] + red[3];

  if (d4 == 0) {
    out[OUT_IDX + q] = (float)idx;
    atomicAdd(&counts[idx], 1);
  }

  // ---- last-block finalize ----
  __syncthreads();                 // all stores/atomics of this block issued
  __threadfence();                 // device-scope release
  __shared__ int amlast;
  if (threadIdx.x == 0)
    amlast = (atomicAdd(done, 1) == EPI_BLOCKS - 1) ? 1 : 0;
  __syncthreads();
  if (!amlast) return;
  __threadfence();                 // acquire: see all blocks' part/counts

  int tid = threadIdx.x;
  float lsum = 0.f;
  for (int i = tid; i < EPI_BLOCKS; i += 256) lsum += part[i];
  float es = 0.f;
  for (int i = tid; i < M_CODES; i += 256) {
    float p = (float)counts[i] * (1.0f / 65536.0f);
    es += p * logf(p + 1e-10f);
  }
  for (int off = 32; off; off >>= 1) {
    lsum += __shfl_down(lsum, off);
    es += __shfl_down(es, off);
  }
  __shared__ float redl[4], rede[4];
  if ((tid & 63) == 0) {
    redl[tid >> 6] = lsum;
    rede[tid >> 6] = es;
  }
  __syncthreads();
  if (tid == 0) {
    out[OUT_LOSS] = (redl[0] + redl[1] + redl[2] + redl[3]) * (1.0f / 8388608.0f);
    out[OUT_PERP] = expf(-(rede[0] + rede[1] + rede[2] + rede[3]));
  }
}

extern "C" void kernel_launch(void* const* d_in, const int* in_sizes, int n_in,
                              void* d_out, int out_size, void* d_ws, size_t ws_size,
                              hipStream_t stream) {
  const float* x = (const float*)d_in[0];
  const float* w = (const float*)d_in[1];
  float* out = (float*)d_out;
  char* ws = (char*)d_ws;
  float* l2k = (float*)(ws + WS_L2K);
  __bf16* pb = (__bf16*)(ws + WS_PB);
  int* bidx = (int*)(ws + WS_IDX);
  float* part = (float*)(ws + WS_PART);
  int* counts = (int*)(ws + WS_CNT);
  int* done = (int*)(ws + WS_DONE);

  prep_kernel<<<256, 256, 0, stream>>>(w, l2k, pb, counts, done);
  argmin_mfma<<<BN_TOT / QB, 512, 0, stream>>>(x, pb, l2k, w, bidx);
  epilogue_kernel<<<EPI_BLOCKS, 256, 0, stream>>>(x, w, bidx, out, part, counts, done);
}

// Round 10
// 526.775 us; speedup vs baseline: 2.2074x; 2.2074x over previous
//
#include <hip/hip_runtime.h>
#include <hip/hip_bf16.h>
#include <math.h>

// Problem constants
#define D_DIM 128
#define M_CODES 2048
#define BN_TOT 65536           // B*N = 16*4096
#define OUT_LOSS 8388608       // flat offset of loss
#define OUT_PERP 8388609       // flat offset of perp
#define OUT_IDX 8388610        // flat offset of indices
#define MARGIN 2e-3f           // covers ref fp32 noise (~1.6e-5) + bf16-split err

#define QB 128                 // queries per argmin block (4 q-groups x 2 slices)
#define EPI_BLOCKS 8192

// ws byte offsets
#define WS_L2K 0               // float l2k[2048]              (8 KB)
#define WS_PB 8192             // bf16 packed codebook, 1 MB: 64 pchunks x 16 KB
#define WS_IDX 1056768         // int best_idx[65536]          (256 KB)
#define WS_PART 1318912        // float loss_part[8192]        (32 KB)
#define WS_CNT 1351680         // int counts[2048]             (8 KB)

typedef __bf16 bf16x8 __attribute__((ext_vector_type(8)));
typedef float f32x4 __attribute__((ext_vector_type(4)));

// async 16B/lane global->LDS copy: LDS dest is wave-uniform base + lane*16
#define GLOAD_LDS16(g, l)                                         \
  __builtin_amdgcn_global_load_lds(                               \
      (const __attribute__((address_space(1))) void*)(g),         \
      (__attribute__((address_space(3))) void*)(l), 16, 0, 0)

#define MFMA16(a, b, c) __builtin_amdgcn_mfma_f32_16x16x32_bf16((a), (b), (c), 0, 0, 0)

// ---------------------------------------------------------------------------
// prep: fuses (a) emulated-np ||k||^2 (terms rounded fp32, fp64 sum, round
// back -> matches ref within ~1 ulp), (b) codebook prepack, (c) counts
// zeroing. Grid 256x256.
//
// Pack layout (UNCHANGED, verified v3..v9): pchunk p (32 codes) occupies
// bytes [p*16384, (p+1)*16384). granule g = p*16 + cid (1 KB):
//   cid in [0,8):  hi part, ks = cid>>1, wc = cid&1
//   cid in [8,16): lo part, k2 = cid-8, ks = k2>>1, wc = k2&1
// lane l (col=l&15, quad=l>>4), elem j in [0,8):
//   value = w[p*32 + wc*16 + col][ks*32 + quad*8 + j]
// ---------------------------------------------------------------------------
__global__ __launch_bounds__(256) void prep_kernel(const float* __restrict__ w,
                                                   float* __restrict__ l2k,
                                                   __bf16* __restrict__ pb,
                                                   int* __restrict__ counts) {
  int gid = blockIdx.x * 256 + threadIdx.x;

  if (gid < M_CODES) {
    const float4* p = (const float4*)(w + (size_t)gid * D_DIM);
    double s = 0.0;
#pragma unroll
    for (int j = 0; j < 32; ++j) {
      float4 v = p[j];
      s += (double)(v.x * v.x);
      s += (double)(v.y * v.y);
      s += (double)(v.z * v.z);
      s += (double)(v.w * v.w);
    }
    l2k[gid] = (float)s;
    counts[gid] = 0;
  }

  // pack: gid is a lane-granule id, 65536 total
  int lane = gid & 63;
  int g = gid >> 6;                          // granule 0..1023
  int cid = g & 15;
  int p = g >> 4;
  int k2 = cid & 7;
  int ks = k2 >> 1;
  int wc = k2 & 1;
  int code = p * 32 + wc * 16 + (lane & 15);
  int koff = ks * 32 + (lane >> 4) * 8;
  const float* src = w + (size_t)code * D_DIM + koff;
  float4 u = *(const float4*)src;
  float4 v = *(const float4*)(src + 4);
  float f[8] = {u.x, u.y, u.z, u.w, v.x, v.y, v.z, v.w};
  bf16x8 o;
#pragma unroll
  for (int j = 0; j < 8; ++j) {
    __bf16 hh = (__bf16)f[j];
    o[j] = (cid < 8) ? hh : (__bf16)(f[j] - (float)hh);
  }
  *(bf16x8*)(pb + (size_t)g * 512 + lane * 8) = o;
}

// max-form merge: (b,s)=best/second-best of acc (=sim-0.5*l2k; argmax),
// first-index tie-break
__device__ __forceinline__ void merge_bs(float& b, float& s, int& i,
                                         float ob, float os, int oi) {
  if (ob > b) {
    s = fmaxf(b, os);
    b = ob;
    i = oi;
  } else if (ob < b) {
    s = fmaxf(s, ob);
  } else {           // tie: gap 0 -> flagged -> in-block fixup resolves exactly
    s = b;
    if (oi < i) i = oi;
  }
}

// ---------------------------------------------------------------------------
// MFMA argmin v10 (= verified v9 argmin, unchanged). QB=128, 8-wave blocks,
// 1 round (grid 512 = 2 blocks/CU), no ks-prefetch (frees regs, no spill),
// in-block fp64 fixup tail for flagged queries (byte-identical numerics to
// the old fixup_kernel; saves a launch, no fences needed — block-local).
// v9 lesson kept OUT of this file: last-block finalize with per-block
// device fences cost ~600us of L2 writeback storms (epilogue 695us).
// ---------------------------------------------------------------------------
__global__ __launch_bounds__(512, 4) void argmin_mfma(
    const float* __restrict__ x, const __bf16* __restrict__ pb,
    const float* __restrict__ l2k, const float* __restrict__ w,
    int* __restrict__ best_idx) {
  __shared__ __align__(16) unsigned char ldsB[2 * 32768];
  __shared__ float redB[8][32];
  __shared__ float redS[8][32];
  __shared__ int redI[8][32];
  __shared__ int flcnt;
  __shared__ int flist[QB];
  __shared__ float l2q_sh;

  const int tid = threadIdx.x;
  const int wv = tid >> 6;        // wave 0..7
  const int lane = tid & 63;
  const int col = lane & 15;      // MFMA n-index / A m-index
  const int quad = lane >> 4;     // 0..3
  const int wc = wv & 1;          // code-slice within pchunk
  const int wq = wv >> 1;         // query group 0..3 (32 q each)
  const int q0 = blockIdx.x * QB;

  if (tid == 0) flcnt = 0;

  // ---- A fragments for this wave's 32 queries, fp32 -> hi/lo bf16, in regs
  bf16x8 ah[2][4], al[2][4];
#pragma unroll
  for (int mt = 0; mt < 2; ++mt) {
#pragma unroll
    for (int ks = 0; ks < 4; ++ks) {
      const float* xr =
          x + (size_t)(q0 + wq * 32 + 16 * mt + col) * D_DIM + 32 * ks + 8 * quad;
      float4 u = *(const float4*)xr;
      float4 v = *(const float4*)(xr + 4);
      float f[8] = {u.x, u.y, u.z, u.w, v.x, v.y, v.z, v.w};
      bf16x8 h, l;
#pragma unroll
      for (int j = 0; j < 8; ++j) {
        __bf16 hh = (__bf16)f[j];
        h[j] = hh;
        l[j] = (__bf16)(f[j] - (float)hh);
      }
      ah[mt][ks] = h;
      al[mt][ks] = l;
    }
  }

  // per-lane running argmax state over acc = sim - 0.5*l2k
  float m1[2][4], m2[2][4];
  int bp[2][4];                   // best pchunk id (full index rebuilt later)
#pragma unroll
  for (int mt = 0; mt < 2; ++mt)
#pragma unroll
    for (int r = 0; r < 4; ++r) {
      m1[mt][r] = -3.4e38f;
      m2[mt][r] = -3.4e38f;
      bp[mt][r] = 0;
    }

  const int ldsw = wc * 1024 + lane * 16;
  const float* l2p = l2k + wc * 16 + col;

  // stage chunk ch (64 codes = 32 KB = pchunks 2ch, 2ch+1); 4 granules/wave.
  // db MUST include the per-wave dest offset (+wv*4096) — v6 lesson.
  auto stage = [&](int ch, unsigned char* db) {
    const char* s = (const char*)pb + (size_t)ch * 32768 + wv * 4096 + lane * 16;
#pragma unroll
    for (int i = 0; i < 4; ++i) GLOAD_LDS16(s + i * 1024, db + i * 1024);
  };

  stage(0, ldsB + wv * 4096);     // per-wave dest offset!
  float l2a = l2p[0];
  float l2b = l2p[32];
  __syncthreads();   // drains vmcnt -> stage(0) complete

#pragma unroll 1
  for (int ch = 0; ch < 32; ++ch) {
    const int buf = ch & 1;
    if (ch < 31) stage(ch + 1, ldsB + (buf ^ 1) * 32768 + wv * 4096);
    float l2na = 0.f, l2nb = 0.f;
    if (ch < 31) {                          // l2 for chunk ch+1 (latency hidden)
      l2na = l2p[(2 * ch + 2) * 32];
      l2nb = l2p[(2 * ch + 3) * 32];
    }

    // ---- compute chunk ch: 48 MFMA (plain per-ks loads)
    const unsigned char* rb = ldsB + buf * 32768 + ldsw;
    float ia = -0.5f * l2a, ib = -0.5f * l2b;
    f32x4 a00 = (f32x4){ia, ia, ia, ia};
    f32x4 a10 = (f32x4){ia, ia, ia, ia};
    f32x4 a01 = (f32x4){ib, ib, ib, ib};
    f32x4 a11 = (f32x4){ib, ib, ib, ib};

#pragma unroll
    for (int ks = 0; ks < 4; ++ks) {
      bf16x8 bh0 = *(const bf16x8*)(rb + ks * 2048);
      bf16x8 bl0 = *(const bf16x8*)(rb + 8192 + ks * 2048);
      bf16x8 bh1 = *(const bf16x8*)(rb + 16384 + ks * 2048);
      bf16x8 bl1 = *(const bf16x8*)(rb + 24576 + ks * 2048);
      a00 = MFMA16(al[0][ks], bh0, a00);
      a10 = MFMA16(al[1][ks], bh0, a10);
      a01 = MFMA16(al[0][ks], bh1, a01);
      a11 = MFMA16(al[1][ks], bh1, a11);
      a00 = MFMA16(ah[0][ks], bl0, a00);
      a10 = MFMA16(ah[1][ks], bl0, a10);
      a01 = MFMA16(ah[0][ks], bl1, a01);
      a11 = MFMA16(ah[1][ks], bl1, a11);
      a00 = MFMA16(ah[0][ks], bh0, a00);
      a10 = MFMA16(ah[1][ks], bh0, a10);
      a01 = MFMA16(ah[0][ks], bh1, a01);
      a11 = MFMA16(ah[1][ks], bh1, a11);
    }

    // fold (argmax, branchless second-max, pchunk-id index).
    // candidates ascend over (ch, nt) -> strict > keeps first index.
#pragma unroll
    for (int mt = 0; mt < 2; ++mt) {
#pragma unroll
      for (int r = 0; r < 4; ++r) {
        float dd = (mt == 0) ? a00[r] : a10[r];
        bool gt = dd > m1[mt][r];
        m2[mt][r] = fmaxf(m2[mt][r], fminf(m1[mt][r], dd));
        bp[mt][r] = gt ? (ch * 2 + 0) : bp[mt][r];
        m1[mt][r] = fmaxf(m1[mt][r], dd);
      }
    }
#pragma unroll
    for (int mt = 0; mt < 2; ++mt) {
#pragma unroll
      for (int r = 0; r < 4; ++r) {
        float dd = (mt == 0) ? a01[r] : a11[r];
        bool gt = dd > m1[mt][r];
        m2[mt][r] = fmaxf(m2[mt][r], fminf(m1[mt][r], dd));
        bp[mt][r] = gt ? (ch * 2 + 1) : bp[mt][r];
        m1[mt][r] = fmaxf(m1[mt][r], dd);
      }
    }

    l2a = l2na;
    l2b = l2nb;
    __syncthreads();              // next buf staged + this buf reads done
  }

  // ---- Cross-lane reduction: 16 cols per quad-row ----
#pragma unroll
  for (int mt = 0; mt < 2; ++mt) {
#pragma unroll
    for (int r = 0; r < 4; ++r) {
      float b = m1[mt][r], s = m2[mt][r];
      int i = bp[mt][r] * 32 + wc * 16 + col;   // full code index
#pragma unroll
      for (int m = 1; m < 16; m <<= 1) {
        float ob = __shfl_xor(b, m);
        float os = __shfl_xor(s, m);
        int oi = __shfl_xor(i, m);
        merge_bs(b, s, i, ob, os, oi);
      }
      if (col == 0) {
        int qloc = 16 * mt + 4 * quad + r;
        redB[wv][qloc] = b;
        redS[wv][qloc] = s;
        redI[wv][qloc] = i;
      }
    }
  }
  __syncthreads();

  // ---- Final merge across the 2 code-slice waves of each query group ----
  if (tid < QB) {
    int wg = tid >> 5;            // query group 0..3
    int ql = tid & 31;
    float b = -3.4e38f, s = -3.4e38f;
    int i = 0x7fffffff;
    merge_bs(b, s, i, redB[wg * 2 + 0][ql], redS[wg * 2 + 0][ql], redI[wg * 2 + 0][ql]);
    merge_bs(b, s, i, redB[wg * 2 + 1][ql], redS[wg * 2 + 1][ql], redI[wg * 2 + 1][ql]);
    best_idx[q0 + tid] = i;
    // dist gap = 2*(b - s) on acc scale
    if (2.0f * (b - s) < MARGIN) {
      int pos = atomicAdd(&flcnt, 1);
      flist[pos] = tid;           // local query id
    }
  }
  __syncthreads();

  // ---- In-block fixup tail: exact fp64 rescan for flagged queries.
  // Emulates the reference fp32 computation exactly: dist =
  // fl32(fl32(l2q+l2k[c]) - fl32(2*fl32(q.k))), q.k in fp64 rounded once;
  // first-index tie-break. ldsB is dead -> reuse for qs / reductions.
  const int nf = flcnt;
  if (nf > 0) {
    float* qs = (float*)ldsB;                    // 128 floats
    float* redD = (float*)(ldsB + 2048);         // 512 floats
    int* redIx = (int*)(ldsB + 4096);            // 512 ints
    for (int f = 0; f < nf; ++f) {
      int q = q0 + flist[f];
      if (tid < D_DIM) qs[tid] = x[(size_t)q * D_DIM + tid];
      __syncthreads();
      if (tid == 0) {
        double s = 0.0;
        for (int d = 0; d < D_DIM; ++d) {
          float t = qs[d] * qs[d];
          s += (double)t;
        }
        l2q_sh = (float)s;
      }
      __syncthreads();
      const float l2q = l2q_sh;
      float bd = 3.4e38f;
      int bi = 0x7fffffff;
      for (int c = tid; c < M_CODES; c += 512) {
        const float4* wr = (const float4*)(w + (size_t)c * D_DIM);
        double s = 0.0;
#pragma unroll
        for (int j = 0; j < 32; ++j) {
          float4 v = wr[j];
          s = fma((double)qs[j * 4 + 0], (double)v.x, s);
          s = fma((double)qs[j * 4 + 1], (double)v.y, s);
          s = fma((double)qs[j * 4 + 2], (double)v.z, s);
          s = fma((double)qs[j * 4 + 3], (double)v.w, s);
        }
        float simf = (float)s;
        float S = l2q + l2k[c];
        float T = 2.0f * simf;
        float dist = S - T;
        if (dist < bd) { bd = dist; bi = c; }
      }
      redD[tid] = bd;
      redIx[tid] = bi;
      __syncthreads();
      for (int off = 256; off; off >>= 1) {
        if (tid < off) {
          float od = redD[tid + off];
          int oi = redIx[tid + off];
          if (od < redD[tid] || (od == redD[tid] && oi < redIx[tid])) {
            redD[tid] = od;
            redIx[tid] = oi;
          }
        }
        __syncthreads();
      }
      if (tid == 0) best_idx[q] = redIx[0];
      __syncthreads();
    }
  }
}

// ---------------------------------------------------------------------------
// Gather + straight-through output + loss partials + histogram + indices out
// (v8 form — NO fused finalize: per-block device fences cost 600us in v9)
// ---------------------------------------------------------------------------
__global__ __launch_bounds__(256) void epilogue_kernel(const float* __restrict__ x,
                                                       const float* __restrict__ w,
                                                       const int* __restrict__ best_idx,
                                                       float* __restrict__ out,
                                                       float* __restrict__ part,
                                                       int* __restrict__ counts) {
  int gid = blockIdx.x * 256 + threadIdx.x;  // float4 id, 2,097,152 total
  int q = gid >> 5;
  int d4 = gid & 31;
  int idx = best_idx[q];
  float4 xv = ((const float4*)x)[gid];
  float4 wv = ((const float4*)w)[(size_t)idx * 32 + d4];
  float4 o;
  float t0 = wv.x - xv.x; o.x = xv.x + t0; float e0 = o.x - xv.x;
  float t1 = wv.y - xv.y; o.y = xv.y + t1; float e1 = o.y - xv.y;
  float t2 = wv.z - xv.z; o.z = xv.z + t2; float e2 = o.z - xv.z;
  float t3 = wv.w - xv.w; o.w = xv.w + t3; float e3 = o.w - xv.w;
  float ls = e0 * e0 + e1 * e1 + e2 * e2 + e3 * e3;
  ((float4*)out)[gid] = o;

  for (int off = 32; off; off >>= 1) ls += __shfl_down(ls, off);
  __shared__ float red[4];
  if ((threadIdx.x & 63) == 0) red[threadIdx.x >> 6] = ls;
  __syncthreads();
  if (threadIdx.x == 0) part[blockIdx.x] = red[0] + red[1] + red[2] + red[3];

  if (d4 == 0) {
    out[OUT_IDX + q] = (float)idx;
    atomicAdd(&counts[idx], 1);
  }
}

// ---------------------------------------------------------------------------
// Finalize: loss mean + perplexity (separate launch: stream ordering gives
// cross-XCD visibility for free, no per-block fences)
// ---------------------------------------------------------------------------
__global__ __launch_bounds__(256) void finalize_kernel(const int* __restrict__ counts,
                                                       const float* __restrict__ part,
                                                       float* __restrict__ out) {
  int tid = threadIdx.x;
  float ls = 0.f;
  for (int i = tid; i < EPI_BLOCKS; i += 256) ls += part[i];
  float es = 0.f;
  for (int i = tid; i < M_CODES; i += 256) {
    float p = (float)counts[i] * (1.0f / 65536.0f);
    es += p * logf(p + 1e-10f);
  }
  for (int off = 32; off; off >>= 1) {
    ls += __shfl_down(ls, off);
    es += __shfl_down(es, off);
  }
  __shared__ float redl[4], rede[4];
  if ((tid & 63) == 0) {
    redl[tid >> 6] = ls;
    rede[tid >> 6] = es;
  }
  __syncthreads();
  if (tid == 0) {
    out[OUT_LOSS] = (redl[0] + redl[1] + redl[2] + redl[3]) * (1.0f / 8388608.0f);
    out[OUT_PERP] = expf(-(rede[0] + rede[1] + rede[2] + rede[3]));
  }
}

extern "C" void kernel_launch(void* const* d_in, const int* in_sizes, int n_in,
                              void* d_out, int out_size, void* d_ws, size_t ws_size,
                              hipStream_t stream) {
  const float* x = (const float*)d_in[0];
  const float* w = (const float*)d_in[1];
  float* out = (float*)d_out;
  char* ws = (char*)d_ws;
  float* l2k = (float*)(ws + WS_L2K);
  __bf16* pb = (__bf16*)(ws + WS_PB);
  int* bidx = (int*)(ws + WS_IDX);
  float* part = (float*)(ws + WS_PART);
  int* counts = (int*)(ws + WS_CNT);

  prep_kernel<<<256, 256, 0, stream>>>(w, l2k, pb, counts);
  argmin_mfma<<<BN_TOT / QB, 512, 0, stream>>>(x, pb, l2k, w, bidx);
  epilogue_kernel<<<EPI_BLOCKS, 256, 0, stream>>>(x, w, bidx, out, part, counts);
  finalize_kernel<<<1, 256, 0, stream>>>(counts, part, out);
}

// Round 11
// 238.907 us; speedup vs baseline: 4.8671x; 2.2049x over previous
//
#include <hip/hip_runtime.h>
#include <hip/hip_bf16.h>
#include <math.h>

// Problem constants
#define D_DIM 128
#define M_CODES 2048
#define BN_TOT 65536           // B*N = 16*4096
#define OUT_LOSS 8388608       // flat offset of loss
#define OUT_PERP 8388609       // flat offset of perp
#define OUT_IDX 8388610        // flat offset of indices
#define MARGIN 2e-3f           // covers ref fp32 noise (~1.6e-5) + bf16-split err

#define QB 128                 // queries per argmin block (4 q-groups x 2 slices)

// ws byte offsets
#define WS_L2K 0               // float l2k[2048]              (8 KB)
#define WS_PB 8192             // bf16 packed codebook, 1 MB: 64 pchunks x 16 KB
#define WS_IDX 1056768         // int best_idx[65536]          (256 KB)
#define WS_PART 1318912        // float loss_part[8192]        (32 KB)
#define WS_CNT 1351680         // int counts[2048]             (8 KB)
#define WS_FLAGCNT 1359872     // int flag_count               (pad to 1 KB)
#define WS_FLAGGED 1360896     // int flagged[65536]           (256 KB)

typedef __bf16 bf16x8 __attribute__((ext_vector_type(8)));
typedef float f32x4 __attribute__((ext_vector_type(4)));

// async 16B/lane global->LDS copy: LDS dest is wave-uniform base + lane*16
#define GLOAD_LDS16(g, l)                                         \
  __builtin_amdgcn_global_load_lds(                               \
      (const __attribute__((address_space(1))) void*)(g),         \
      (__attribute__((address_space(3))) void*)(l), 16, 0, 0)

#define MFMA16(a, b, c) __builtin_amdgcn_mfma_f32_16x16x32_bf16((a), (b), (c), 0, 0, 0)

// ---------------------------------------------------------------------------
// prep: fuses (a) emulated-np ||k||^2 (terms rounded fp32, fp64 sum, round
// back -> matches ref within ~1 ulp), (b) codebook prepack, (c) counts /
// flag_count zeroing. Grid 256x256.
//
// Pack layout (verified v3..v8): pchunk p (32 codes) occupies bytes
// [p*16384, (p+1)*16384). granule g = p*16 + cid (1 KB):
//   cid in [0,8):  hi part, ks = cid>>1, wc = cid&1
//   cid in [8,16): lo part, k2 = cid-8, ks = k2>>1, wc = k2&1
// lane l (col=l&15, quad=l>>4), elem j in [0,8):
//   value = w[p*32 + wc*16 + col][ks*32 + quad*8 + j]
// ---------------------------------------------------------------------------
__global__ __launch_bounds__(256) void prep_kernel(const float* __restrict__ w,
                                                   float* __restrict__ l2k,
                                                   __bf16* __restrict__ pb,
                                                   int* __restrict__ counts,
                                                   int* __restrict__ flagcnt) {
  int gid = blockIdx.x * 256 + threadIdx.x;

  if (gid < M_CODES) {
    const float4* p = (const float4*)(w + (size_t)gid * D_DIM);
    double s = 0.0;
#pragma unroll
    for (int j = 0; j < 32; ++j) {
      float4 v = p[j];
      s += (double)(v.x * v.x);
      s += (double)(v.y * v.y);
      s += (double)(v.z * v.z);
      s += (double)(v.w * v.w);
    }
    l2k[gid] = (float)s;
    counts[gid] = 0;
    if (gid == 0) *flagcnt = 0;
  }

  // pack: gid is a lane-granule id, 65536 total
  int lane = gid & 63;
  int g = gid >> 6;                          // granule 0..1023
  int cid = g & 15;
  int p = g >> 4;
  int k2 = cid & 7;
  int ks = k2 >> 1;
  int wc = k2 & 1;
  int code = p * 32 + wc * 16 + (lane & 15);
  int koff = ks * 32 + (lane >> 4) * 8;
  const float* src = w + (size_t)code * D_DIM + koff;
  float4 u = *(const float4*)src;
  float4 v = *(const float4*)(src + 4);
  float f[8] = {u.x, u.y, u.z, u.w, v.x, v.y, v.z, v.w};
  bf16x8 o;
#pragma unroll
  for (int j = 0; j < 8; ++j) {
    __bf16 hh = (__bf16)f[j];
    o[j] = (cid < 8) ? hh : (__bf16)(f[j] - (float)hh);
  }
  *(bf16x8*)(pb + (size_t)g * 512 + lane * 8) = o;
}

// max-form merge: (b,s)=best/second-best of acc (=sim-0.5*l2k; argmax),
// first-index tie-break
__device__ __forceinline__ void merge_bs(float& b, float& s, int& i,
                                         float ob, float os, int oi) {
  if (ob > b) {
    s = fmaxf(b, os);
    b = ob;
    i = oi;
  } else if (ob < b) {
    s = fmaxf(s, ob);
  } else {           // tie: gap 0 -> flagged -> fixup resolves exactly
    s = b;
    if (oi < i) i = oi;
  }
}

// ---------------------------------------------------------------------------
// MFMA argmin v11 = EXACT v8 (verified 104us, MfmaUtil 43%, total 237us).
// v9/v10 post-mortem: the in-block fp64 fixup tail + prefetch removal blew
// scratch to ~160MB HBM traffic (argmin 438us, MfmaUtil 9.6%) — the fp64
// rescan tail raises peak register pressure under the 128-reg cap and the
// allocator pushed spills into the hot loop. Reverted wholesale; fixup is
// a separate kernel again. Known-benign residual: ~5.4MB spill (WRITE_SIZE),
// ~20B/thread, measured cost small at 104us.
// ---------------------------------------------------------------------------
__global__ __launch_bounds__(512, 4) void argmin_mfma(
    const float* __restrict__ x, const __bf16* __restrict__ pb,
    const float* __restrict__ l2k, int* __restrict__ best_idx,
    int* __restrict__ flag_count, int* __restrict__ flagged) {
  __shared__ __align__(16) unsigned char ldsB[2 * 32768];
  __shared__ float redB[8][32];
  __shared__ float redS[8][32];
  __shared__ int redI[8][32];

  const int tid = threadIdx.x;
  const int wv = tid >> 6;        // wave 0..7
  const int lane = tid & 63;
  const int col = lane & 15;      // MFMA n-index / A m-index
  const int quad = lane >> 4;     // 0..3
  const int wc = wv & 1;          // code-slice within pchunk
  const int wq = wv >> 1;         // query group 0..3 (32 q each)
  const int q0 = blockIdx.x * QB;

  // ---- A fragments for this wave's 32 queries, fp32 -> hi/lo bf16, in regs
  bf16x8 ah[2][4], al[2][4];
#pragma unroll
  for (int mt = 0; mt < 2; ++mt) {
#pragma unroll
    for (int ks = 0; ks < 4; ++ks) {
      const float* xr =
          x + (size_t)(q0 + wq * 32 + 16 * mt + col) * D_DIM + 32 * ks + 8 * quad;
      float4 u = *(const float4*)xr;
      float4 v = *(const float4*)(xr + 4);
      float f[8] = {u.x, u.y, u.z, u.w, v.x, v.y, v.z, v.w};
      bf16x8 h, l;
#pragma unroll
      for (int j = 0; j < 8; ++j) {
        __bf16 hh = (__bf16)f[j];
        h[j] = hh;
        l[j] = (__bf16)(f[j] - (float)hh);
      }
      ah[mt][ks] = h;
      al[mt][ks] = l;
    }
  }

  // per-lane running argmax state over acc = sim - 0.5*l2k
  float m1[2][4], m2[2][4];
  int bp[2][4];                   // best pchunk id (full index rebuilt later)
#pragma unroll
  for (int mt = 0; mt < 2; ++mt)
#pragma unroll
    for (int r = 0; r < 4; ++r) {
      m1[mt][r] = -3.4e38f;
      m2[mt][r] = -3.4e38f;
      bp[mt][r] = 0;
    }

  const int ldsw = wc * 1024 + lane * 16;
  const float* l2p = l2k + wc * 16 + col;

  // stage chunk ch (64 codes = 32 KB = pchunks 2ch, 2ch+1); 4 granules/wave.
  // db MUST include the per-wave dest offset (+wv*4096) — v6 lesson.
  auto stage = [&](int ch, unsigned char* db) {
    const char* s = (const char*)pb + (size_t)ch * 32768 + wv * 4096 + lane * 16;
#pragma unroll
    for (int i = 0; i < 4; ++i) GLOAD_LDS16(s + i * 1024, db + i * 1024);
  };

  stage(0, ldsB + wv * 4096);     // per-wave dest offset!
  float l2a = l2p[0];
  float l2b = l2p[32];
  __syncthreads();   // drains vmcnt -> stage(0) complete

#pragma unroll 1
  for (int ch = 0; ch < 32; ++ch) {
    const int buf = ch & 1;
    if (ch < 31) stage(ch + 1, ldsB + (buf ^ 1) * 32768 + wv * 4096);
    float l2na = 0.f, l2nb = 0.f;
    if (ch < 31) {                          // l2 for chunk ch+1 (latency hidden)
      l2na = l2p[(2 * ch + 2) * 32];
      l2nb = l2p[(2 * ch + 3) * 32];
    }

    // ---- compute chunk ch: 48 MFMA, explicit 1-ks-ahead B prefetch ----
    const unsigned char* rb = ldsB + buf * 32768 + ldsw;
    float ia = -0.5f * l2a, ib = -0.5f * l2b;
    f32x4 a00 = (f32x4){ia, ia, ia, ia};
    f32x4 a10 = (f32x4){ia, ia, ia, ia};
    f32x4 a01 = (f32x4){ib, ib, ib, ib};
    f32x4 a11 = (f32x4){ib, ib, ib, ib};

    bf16x8 h0 = *(const bf16x8*)(rb);              // ks cur, nt0 hi
    bf16x8 l0 = *(const bf16x8*)(rb + 8192);       // ks cur, nt0 lo
    bf16x8 h1 = *(const bf16x8*)(rb + 16384);      // ks cur, nt1 hi
    bf16x8 l1 = *(const bf16x8*)(rb + 24576);      // ks cur, nt1 lo

#define DO_KS(KS, PRE)                                                    \
    {                                                                     \
      bf16x8 nh0, nl0, nh1, nl1;                                          \
      if (PRE) {                                                          \
        nh0 = *(const bf16x8*)(rb + ((KS) + 1) * 2048);                   \
        nl0 = *(const bf16x8*)(rb + 8192 + ((KS) + 1) * 2048);            \
        nh1 = *(const bf16x8*)(rb + 16384 + ((KS) + 1) * 2048);           \
        nl1 = *(const bf16x8*)(rb + 24576 + ((KS) + 1) * 2048);           \
      }                                                                   \
      a00 = MFMA16(al[0][KS], h0, a00);                                   \
      a10 = MFMA16(al[1][KS], h0, a10);                                   \
      a01 = MFMA16(al[0][KS], h1, a01);                                   \
      a11 = MFMA16(al[1][KS], h1, a11);                                   \
      a00 = MFMA16(ah[0][KS], l0, a00);                                   \
      a10 = MFMA16(ah[1][KS], l0, a10);                                   \
      a01 = MFMA16(ah[0][KS], l1, a01);                                   \
      a11 = MFMA16(ah[1][KS], l1, a11);                                   \
      a00 = MFMA16(ah[0][KS], h0, a00);                                   \
      a10 = MFMA16(ah[1][KS], h0, a10);                                   \
      a01 = MFMA16(ah[0][KS], h1, a01);                                   \
      a11 = MFMA16(ah[1][KS], h1, a11);                                   \
      if (PRE) { h0 = nh0; l0 = nl0; h1 = nh1; l1 = nl1; }                \
    }
    DO_KS(0, 1)
    DO_KS(1, 1)
    DO_KS(2, 1)
    DO_KS(3, 0)
#undef DO_KS

    // fold (argmax, branchless second-max, pchunk-id index).
    // candidates ascend over (ch, nt) -> strict > keeps first index.
#pragma unroll
    for (int mt = 0; mt < 2; ++mt) {
#pragma unroll
      for (int r = 0; r < 4; ++r) {
        float dd = (mt == 0) ? a00[r] : a10[r];
        bool gt = dd > m1[mt][r];
        m2[mt][r] = fmaxf(m2[mt][r], fminf(m1[mt][r], dd));
        bp[mt][r] = gt ? (ch * 2 + 0) : bp[mt][r];
        m1[mt][r] = fmaxf(m1[mt][r], dd);
      }
    }
#pragma unroll
    for (int mt = 0; mt < 2; ++mt) {
#pragma unroll
      for (int r = 0; r < 4; ++r) {
        float dd = (mt == 0) ? a01[r] : a11[r];
        bool gt = dd > m1[mt][r];
        m2[mt][r] = fmaxf(m2[mt][r], fminf(m1[mt][r], dd));
        bp[mt][r] = gt ? (ch * 2 + 1) : bp[mt][r];
        m1[mt][r] = fmaxf(m1[mt][r], dd);
      }
    }

    l2a = l2na;
    l2b = l2nb;
    __syncthreads();              // next buf staged + this buf reads done
  }

  // ---- Cross-lane reduction: 16 cols per quad-row ----
#pragma unroll
  for (int mt = 0; mt < 2; ++mt) {
#pragma unroll
    for (int r = 0; r < 4; ++r) {
      float b = m1[mt][r], s = m2[mt][r];
      int i = bp[mt][r] * 32 + wc * 16 + col;   // full code index
#pragma unroll
      for (int m = 1; m < 16; m <<= 1) {
        float ob = __shfl_xor(b, m);
        float os = __shfl_xor(s, m);
        int oi = __shfl_xor(i, m);
        merge_bs(b, s, i, ob, os, oi);
      }
      if (col == 0) {
        int qloc = 16 * mt + 4 * quad + r;
        redB[wv][qloc] = b;
        redS[wv][qloc] = s;
        redI[wv][qloc] = i;
      }
    }
  }
  __syncthreads();

  // ---- Final merge across the 2 code-slice waves of each query group ----
  if (tid < QB) {
    int wg = tid >> 5;            // query group 0..3
    int ql = tid & 31;
    float b = -3.4e38f, s = -3.4e38f;
    int i = 0x7fffffff;
    merge_bs(b, s, i, redB[wg * 2 + 0][ql], redS[wg * 2 + 0][ql], redI[wg * 2 + 0][ql]);
    merge_bs(b, s, i, redB[wg * 2 + 1][ql], redS[wg * 2 + 1][ql], redI[wg * 2 + 1][ql]);
    best_idx[q0 + tid] = i;
    // dist gap = 2*(b - s) on acc scale
    if (2.0f * (b - s) < MARGIN) {
      int pos = atomicAdd(flag_count, 1);
      flagged[pos] = q0 + tid;
    }
  }
}

// ---------------------------------------------------------------------------
// Fixup: for flagged queries, emulate the reference's fp32 computation:
//   dist = fl32( fl32(l2q32 + l2k32[c]) - fl32(2 * fl32(q.k)) )
// q.k exact in fp64 then rounded once to fp32. First-index tie-break.
// ---------------------------------------------------------------------------
__global__ __launch_bounds__(256) void fixup_kernel(const float* __restrict__ x,
                                                    const float* __restrict__ w,
                                                    const float* __restrict__ l2k32,
                                                    const int* __restrict__ flagged,
                                                    const int* __restrict__ flag_count,
                                                    int* __restrict__ best_idx) {
  __shared__ float qs[D_DIM];
  __shared__ float l2q_sh;
  __shared__ float redD[256];
  __shared__ int redI[256];
  const int tid = threadIdx.x;
  const int n = *flag_count;
  for (int f = blockIdx.x; f < n; f += gridDim.x) {
    __syncthreads();
    int q = flagged[f];
    if (tid < D_DIM) qs[tid] = x[(size_t)q * D_DIM + tid];
    __syncthreads();
    if (tid == 0) {
      double s = 0.0;
      for (int d = 0; d < D_DIM; ++d) {
        float t = qs[d] * qs[d];
        s += (double)t;
      }
      l2q_sh = (float)s;
    }
    __syncthreads();
    const float l2q = l2q_sh;
    float bd = 3.4e38f;
    int bi = 0x7fffffff;
    for (int c = tid; c < M_CODES; c += 256) {
      const float4* wr = (const float4*)(w + (size_t)c * D_DIM);
      double s = 0.0;
#pragma unroll
      for (int j = 0; j < 32; ++j) {
        float4 v = wr[j];
        s = fma((double)qs[j * 4 + 0], (double)v.x, s);
        s = fma((double)qs[j * 4 + 1], (double)v.y, s);
        s = fma((double)qs[j * 4 + 2], (double)v.z, s);
        s = fma((double)qs[j * 4 + 3], (double)v.w, s);
      }
      float simf = (float)s;
      float S = l2q + l2k32[c];
      float T = 2.0f * simf;
      float dist = S - T;
      if (dist < bd) { bd = dist; bi = c; }
    }
    redD[tid] = bd;
    redI[tid] = bi;
    __syncthreads();
    for (int off = 128; off; off >>= 1) {
      if (tid < off) {
        float od = redD[tid + off];
        int oi = redI[tid + off];
        if (od < redD[tid] || (od == redD[tid] && oi < redI[tid])) {
          redD[tid] = od;
          redI[tid] = oi;
        }
      }
      __syncthreads();
    }
    if (tid == 0) best_idx[q] = redI[0];
  }
}

// ---------------------------------------------------------------------------
// Gather + straight-through output + loss partials + histogram + indices out
// ---------------------------------------------------------------------------
__global__ __launch_bounds__(256) void epilogue_kernel(const float* __restrict__ x,
                                                       const float* __restrict__ w,
                                                       const int* __restrict__ best_idx,
                                                       float* __restrict__ out,
                                                       float* __restrict__ part,
                                                       int* __restrict__ counts) {
  int gid = blockIdx.x * 256 + threadIdx.x;  // float4 id, 2,097,152 total
  int q = gid >> 5;
  int d4 = gid & 31;
  int idx = best_idx[q];
  float4 xv = ((const float4*)x)[gid];
  float4 wv = ((const float4*)w)[(size_t)idx * 32 + d4];
  float4 o;
  float t0 = wv.x - xv.x; o.x = xv.x + t0; float e0 = o.x - xv.x;
  float t1 = wv.y - xv.y; o.y = xv.y + t1; float e1 = o.y - xv.y;
  float t2 = wv.z - xv.z; o.z = xv.z + t2; float e2 = o.z - xv.z;
  float t3 = wv.w - xv.w; o.w = xv.w + t3; float e3 = o.w - xv.w;
  float ls = e0 * e0 + e1 * e1 + e2 * e2 + e3 * e3;
  ((float4*)out)[gid] = o;

  for (int off = 32; off; off >>= 1) ls += __shfl_down(ls, off);
  __shared__ float red[4];
  if ((threadIdx.x & 63) == 0) red[threadIdx.x >> 6] = ls;
  __syncthreads();
  if (threadIdx.x == 0) part[blockIdx.x] = red[0] + red[1] + red[2] + red[3];

  if (d4 == 0) {
    out[OUT_IDX + q] = (float)idx;
    atomicAdd(&counts[idx], 1);
  }
}

// ---------------------------------------------------------------------------
// Finalize: loss mean + perplexity
// ---------------------------------------------------------------------------
__global__ __launch_bounds__(256) void finalize_kernel(const int* __restrict__ counts,
                                                       const float* __restrict__ part,
                                                       float* __restrict__ out) {
  int tid = threadIdx.x;
  float ls = 0.f;
  for (int i = tid; i < 8192; i += 256) ls += part[i];
  float es = 0.f;
  for (int i = tid; i < M_CODES; i += 256) {
    float p = (float)counts[i] * (1.0f / 65536.0f);
    es += p * logf(p + 1e-10f);
  }
  for (int off = 32; off; off >>= 1) {
    ls += __shfl_down(ls, off);
    es += __shfl_down(es, off);
  }
  __shared__ float redl[4], rede[4];
  if ((tid & 63) == 0) {
    redl[tid >> 6] = ls;
    rede[tid >> 6] = es;
  }
  __syncthreads();
  if (tid == 0) {
    out[OUT_LOSS] = (redl[0] + redl[1] + redl[2] + redl[3]) * (1.0f / 8388608.0f);
    out[OUT_PERP] = expf(-(rede[0] + rede[1] + rede[2] + rede[3]));
  }
}

extern "C" void kernel_launch(void* const* d_in, const int* in_sizes, int n_in,
                              void* d_out, int out_size, void* d_ws, size_t ws_size,
                              hipStream_t stream) {
  const float* x = (const float*)d_in[0];
  const float* w = (const float*)d_in[1];
  float* out = (float*)d_out;
  char* ws = (char*)d_ws;
  float* l2k = (float*)(ws + WS_L2K);
  __bf16* pb = (__bf16*)(ws + WS_PB);
  int* bidx = (int*)(ws + WS_IDX);
  float* part = (float*)(ws + WS_PART);
  int* counts = (int*)(ws + WS_CNT);
  int* flagcnt = (int*)(ws + WS_FLAGCNT);
  int* flagged = (int*)(ws + WS_FLAGGED);

  prep_kernel<<<256, 256, 0, stream>>>(w, l2k, pb, counts, flagcnt);
  argmin_mfma<<<BN_TOT / QB, 512, 0, stream>>>(x, pb, l2k, bidx, flagcnt, flagged);
  fixup_kernel<<<256, 256, 0, stream>>>(x, w, l2k, flagged, flagcnt, bidx);
  epilogue_kernel<<<8192, 256, 0, stream>>>(x, w, bidx, out, part, counts);
  finalize_kernel<<<1, 256, 0, stream>>>(counts, part, out);
}

// Round 12
// 229.597 us; speedup vs baseline: 5.0645x; 1.0405x over previous
//
#include <hip/hip_runtime.h>
#include <hip/hip_bf16.h>
#include <math.h>

// Problem constants
#define D_DIM 128
#define M_CODES 2048
#define BN_TOT 65536           // B*N = 16*4096
#define OUT_LOSS 8388608       // flat offset of loss
#define OUT_PERP 8388609       // flat offset of perp
#define OUT_IDX 8388610        // flat offset of indices
#define MARGIN 2e-3f           // covers ref fp32 noise (~1.6e-5) + bf16-split err

#define QB 128                 // queries per argmin block (4 q-groups x 2 slices)

// ws byte offsets
#define WS_L2K 0               // float l2k[2048]              (8 KB)
#define WS_PB 8192             // bf16 packed codebook, 1 MB: 64 pchunks x 16 KB
#define WS_IDX 1056768         // int best_idx[65536]          (256 KB)
#define WS_PART 1318912        // float loss_part[513 used]    (32 KB)
#define WS_CNT 1351680         // int counts[2048]             (8 KB)
#define WS_FLAGCNT 1359872     // int flag_count               (pad to 1 KB)
#define WS_FLAGGED 1360896     // int flagged[65536]           (256 KB)

typedef __bf16 bf16x8 __attribute__((ext_vector_type(8)));
typedef float f32x4 __attribute__((ext_vector_type(4)));

// async 16B/lane global->LDS copy: LDS dest is wave-uniform base + lane*16
#define GLOAD_LDS16(g, l)                                         \
  __builtin_amdgcn_global_load_lds(                               \
      (const __attribute__((address_space(1))) void*)(g),         \
      (__attribute__((address_space(3))) void*)(l), 16, 0, 0)

#define MFMA16(a, b, c) __builtin_amdgcn_mfma_f32_16x16x32_bf16((a), (b), (c), 0, 0, 0)

// ---------------------------------------------------------------------------
// prep: (a) emulated-np ||k||^2 (fp32-rounded terms, fp64 sum, round back),
// (b) codebook prepack, (c) counts / flag_count / part[512] zeroing.
// Pack layout (verified v3..v11): pchunk p (32 codes) = bytes
// [p*16384,(p+1)*16384); granule g = p*16 + cid; cid<8 hi (ks=cid>>1,
// wc=cid&1), cid>=8 lo; lane l: value = w[p*32+wc*16+(l&15)][ks*32+(l>>4)*8+j]
// ---------------------------------------------------------------------------
__global__ __launch_bounds__(256) void prep_kernel(const float* __restrict__ w,
                                                   float* __restrict__ l2k,
                                                   __bf16* __restrict__ pb,
                                                   int* __restrict__ counts,
                                                   int* __restrict__ flagcnt,
                                                   float* __restrict__ part) {
  int gid = blockIdx.x * 256 + threadIdx.x;

  if (gid < M_CODES) {
    const float4* p = (const float4*)(w + (size_t)gid * D_DIM);
    double s = 0.0;
#pragma unroll
    for (int j = 0; j < 32; ++j) {
      float4 v = p[j];
      s += (double)(v.x * v.x);
      s += (double)(v.y * v.y);
      s += (double)(v.z * v.z);
      s += (double)(v.w * v.w);
    }
    l2k[gid] = (float)s;
    counts[gid] = 0;
    if (gid == 0) *flagcnt = 0;
    if (gid == 1) part[512] = 0.f;     // fixup loss slot
  }

  // pack: gid is a lane-granule id, 65536 total
  int lane = gid & 63;
  int g = gid >> 6;                          // granule 0..1023
  int cid = g & 15;
  int p = g >> 4;
  int k2 = cid & 7;
  int ks = k2 >> 1;
  int wc = k2 & 1;
  int code = p * 32 + wc * 16 + (lane & 15);
  int koff = ks * 32 + (lane >> 4) * 8;
  const float* src = w + (size_t)code * D_DIM + koff;
  float4 u = *(const float4*)src;
  float4 v = *(const float4*)(src + 4);
  float f[8] = {u.x, u.y, u.z, u.w, v.x, v.y, v.z, v.w};
  bf16x8 o;
#pragma unroll
  for (int j = 0; j < 8; ++j) {
    __bf16 hh = (__bf16)f[j];
    o[j] = (cid < 8) ? hh : (__bf16)(f[j] - (float)hh);
  }
  *(bf16x8*)(pb + (size_t)g * 512 + lane * 8) = o;
}

// max-form merge: (b,s)=best/second-best of acc (=sim-0.5*l2k; argmax),
// first-index tie-break
__device__ __forceinline__ void merge_bs(float& b, float& s, int& i,
                                         float ob, float os, int oi) {
  if (ob > b) {
    s = fmaxf(b, os);
    b = ob;
    i = oi;
  } else if (ob < b) {
    s = fmaxf(s, ob);
  } else {           // tie: gap 0 -> flagged -> fixup resolves exactly
    s = b;
    if (oi < i) i = oi;
  }
}

// ---------------------------------------------------------------------------
// MFMA argmin v12 = v8/v11 main loop (verified 104-107us) + FUSED epilogue
// tail for this block's UNFLAGGED queries (gather + STE out + loss partial
// + histogram + idx-out). Block-local only — no fences (v9's 600us fence
// storm came from device-scope fences, not fusion). Flagged queries are
// skipped here; the fixup kernel performs their epilogue after correcting
// the index. Saves the 8192-block epilogue launch (~20us kernel + ~20us gap,
// residue model from v8 vs v10: one launch+kernel ~= 20-45us).
// Tail is light fp32 gather code (no fp64, no unroll pragmas) to avoid the
// v10 register-allocation catastrophe; gate = WRITE_SIZE ~38MB (32 out +
// 5.4 known-benign spill), revert if >>.
// ---------------------------------------------------------------------------
__global__ __launch_bounds__(512, 4) void argmin_mfma(
    const float* __restrict__ x, const __bf16* __restrict__ pb,
    const float* __restrict__ l2k, const float* __restrict__ w,
    float* __restrict__ out, int* __restrict__ best_idx,
    int* __restrict__ flag_count, int* __restrict__ flagged,
    float* __restrict__ part, int* __restrict__ counts) {
  __shared__ __align__(16) unsigned char ldsB[2 * 32768];
  __shared__ float redB[8][32];
  __shared__ float redS[8][32];
  __shared__ int redI[8][32];
  __shared__ int flagmask[QB];
  __shared__ int bidx_sh[QB];
  __shared__ float lred[8];

  const int tid = threadIdx.x;
  const int wv = tid >> 6;        // wave 0..7
  const int lane = tid & 63;
  const int col = lane & 15;      // MFMA n-index / A m-index
  const int quad = lane >> 4;     // 0..3
  const int wc = wv & 1;          // code-slice within pchunk
  const int wq = wv >> 1;         // query group 0..3 (32 q each)
  const int q0 = blockIdx.x * QB;

  // ---- A fragments for this wave's 32 queries, fp32 -> hi/lo bf16, in regs
  bf16x8 ah[2][4], al[2][4];
#pragma unroll
  for (int mt = 0; mt < 2; ++mt) {
#pragma unroll
    for (int ks = 0; ks < 4; ++ks) {
      const float* xr =
          x + (size_t)(q0 + wq * 32 + 16 * mt + col) * D_DIM + 32 * ks + 8 * quad;
      float4 u = *(const float4*)xr;
      float4 v = *(const float4*)(xr + 4);
      float f[8] = {u.x, u.y, u.z, u.w, v.x, v.y, v.z, v.w};
      bf16x8 h, l;
#pragma unroll
      for (int j = 0; j < 8; ++j) {
        __bf16 hh = (__bf16)f[j];
        h[j] = hh;
        l[j] = (__bf16)(f[j] - (float)hh);
      }
      ah[mt][ks] = h;
      al[mt][ks] = l;
    }
  }

  // per-lane running argmax state over acc = sim - 0.5*l2k
  float m1[2][4], m2[2][4];
  int bp[2][4];                   // best pchunk id (full index rebuilt later)
#pragma unroll
  for (int mt = 0; mt < 2; ++mt)
#pragma unroll
    for (int r = 0; r < 4; ++r) {
      m1[mt][r] = -3.4e38f;
      m2[mt][r] = -3.4e38f;
      bp[mt][r] = 0;
    }

  const int ldsw = wc * 1024 + lane * 16;
  const float* l2p = l2k + wc * 16 + col;

  // stage chunk ch (64 codes = 32 KB = pchunks 2ch, 2ch+1); 4 granules/wave.
  // db MUST include the per-wave dest offset (+wv*4096) — v6 lesson.
  auto stage = [&](int ch, unsigned char* db) {
    const char* s = (const char*)pb + (size_t)ch * 32768 + wv * 4096 + lane * 16;
#pragma unroll
    for (int i = 0; i < 4; ++i) GLOAD_LDS16(s + i * 1024, db + i * 1024);
  };

  stage(0, ldsB + wv * 4096);     // per-wave dest offset!
  float l2a = l2p[0];
  float l2b = l2p[32];
  __syncthreads();   // drains vmcnt -> stage(0) complete

#pragma unroll 1
  for (int ch = 0; ch < 32; ++ch) {
    const int buf = ch & 1;
    if (ch < 31) stage(ch + 1, ldsB + (buf ^ 1) * 32768 + wv * 4096);
    float l2na = 0.f, l2nb = 0.f;
    if (ch < 31) {                          // l2 for chunk ch+1 (latency hidden)
      l2na = l2p[(2 * ch + 2) * 32];
      l2nb = l2p[(2 * ch + 3) * 32];
    }

    // ---- compute chunk ch: 48 MFMA, explicit 1-ks-ahead B prefetch ----
    const unsigned char* rb = ldsB + buf * 32768 + ldsw;
    float ia = -0.5f * l2a, ib = -0.5f * l2b;
    f32x4 a00 = (f32x4){ia, ia, ia, ia};
    f32x4 a10 = (f32x4){ia, ia, ia, ia};
    f32x4 a01 = (f32x4){ib, ib, ib, ib};
    f32x4 a11 = (f32x4){ib, ib, ib, ib};

    bf16x8 h0 = *(const bf16x8*)(rb);              // ks cur, nt0 hi
    bf16x8 l0 = *(const bf16x8*)(rb + 8192);       // ks cur, nt0 lo
    bf16x8 h1 = *(const bf16x8*)(rb + 16384);      // ks cur, nt1 hi
    bf16x8 l1 = *(const bf16x8*)(rb + 24576);      // ks cur, nt1 lo

#define DO_KS(KS, PRE)                                                    \
    {                                                                     \
      bf16x8 nh0, nl0, nh1, nl1;                                          \
      if (PRE) {                                                          \
        nh0 = *(const bf16x8*)(rb + ((KS) + 1) * 2048);                   \
        nl0 = *(const bf16x8*)(rb + 8192 + ((KS) + 1) * 2048);            \
        nh1 = *(const bf16x8*)(rb + 16384 + ((KS) + 1) * 2048);           \
        nl1 = *(const bf16x8*)(rb + 24576 + ((KS) + 1) * 2048);           \
      }                                                                   \
      a00 = MFMA16(al[0][KS], h0, a00);                                   \
      a10 = MFMA16(al[1][KS], h0, a10);                                   \
      a01 = MFMA16(al[0][KS], h1, a01);                                   \
      a11 = MFMA16(al[1][KS], h1, a11);                                   \
      a00 = MFMA16(ah[0][KS], l0, a00);                                   \
      a10 = MFMA16(ah[1][KS], l0, a10);                                   \
      a01 = MFMA16(ah[0][KS], l1, a01);                                   \
      a11 = MFMA16(ah[1][KS], l1, a11);                                   \
      a00 = MFMA16(ah[0][KS], h0, a00);                                   \
      a10 = MFMA16(ah[1][KS], h0, a10);                                   \
      a01 = MFMA16(ah[0][KS], h1, a01);                                   \
      a11 = MFMA16(ah[1][KS], h1, a11);                                   \
      if (PRE) { h0 = nh0; l0 = nl0; h1 = nh1; l1 = nl1; }                \
    }
    DO_KS(0, 1)
    DO_KS(1, 1)
    DO_KS(2, 1)
    DO_KS(3, 0)
#undef DO_KS

    // fold (argmax, branchless second-max, pchunk-id index).
    // candidates ascend over (ch, nt) -> strict > keeps first index.
#pragma unroll
    for (int mt = 0; mt < 2; ++mt) {
#pragma unroll
      for (int r = 0; r < 4; ++r) {
        float dd = (mt == 0) ? a00[r] : a10[r];
        bool gt = dd > m1[mt][r];
        m2[mt][r] = fmaxf(m2[mt][r], fminf(m1[mt][r], dd));
        bp[mt][r] = gt ? (ch * 2 + 0) : bp[mt][r];
        m1[mt][r] = fmaxf(m1[mt][r], dd);
      }
    }
#pragma unroll
    for (int mt = 0; mt < 2; ++mt) {
#pragma unroll
      for (int r = 0; r < 4; ++r) {
        float dd = (mt == 0) ? a01[r] : a11[r];
        bool gt = dd > m1[mt][r];
        m2[mt][r] = fmaxf(m2[mt][r], fminf(m1[mt][r], dd));
        bp[mt][r] = gt ? (ch * 2 + 1) : bp[mt][r];
        m1[mt][r] = fmaxf(m1[mt][r], dd);
      }
    }

    l2a = l2na;
    l2b = l2nb;
    __syncthreads();              // next buf staged + this buf reads done
  }

  // ---- Cross-lane reduction: 16 cols per quad-row ----
#pragma unroll
  for (int mt = 0; mt < 2; ++mt) {
#pragma unroll
    for (int r = 0; r < 4; ++r) {
      float b = m1[mt][r], s = m2[mt][r];
      int i = bp[mt][r] * 32 + wc * 16 + col;   // full code index
#pragma unroll
      for (int m = 1; m < 16; m <<= 1) {
        float ob = __shfl_xor(b, m);
        float os = __shfl_xor(s, m);
        int oi = __shfl_xor(i, m);
        merge_bs(b, s, i, ob, os, oi);
      }
      if (col == 0) {
        int qloc = 16 * mt + 4 * quad + r;
        redB[wv][qloc] = b;
        redS[wv][qloc] = s;
        redI[wv][qloc] = i;
      }
    }
  }
  __syncthreads();

  // ---- Final merge + flag decision (per query) ----
  if (tid < QB) {
    int wg = tid >> 5;            // query group 0..3
    int ql = tid & 31;
    float b = -3.4e38f, s = -3.4e38f;
    int i = 0x7fffffff;
    merge_bs(b, s, i, redB[wg * 2 + 0][ql], redS[wg * 2 + 0][ql], redI[wg * 2 + 0][ql]);
    merge_bs(b, s, i, redB[wg * 2 + 1][ql], redS[wg * 2 + 1][ql], redI[wg * 2 + 1][ql]);
    best_idx[q0 + tid] = i;
    bidx_sh[tid] = i;
    // dist gap = 2*(b - s) on acc scale
    int fl = (2.0f * (b - s) < MARGIN) ? 1 : 0;
    flagmask[tid] = fl;
    if (fl) {
      int pos = atomicAdd(flag_count, 1);
      flagged[pos] = q0 + tid;
    } else {
      out[OUT_IDX + q0 + tid] = (float)i;   // idx-out + histogram (q-level)
      atomicAdd(&counts[i], 1);
    }
  }
  __syncthreads();

  // ---- Fused epilogue for UNFLAGGED queries of this block ----
  // 128 q x 32 float4 = 4096 float4, 8 iters of 512 threads; coalesced.
  const float4* x4 = (const float4*)x;
  const float4* w4 = (const float4*)w;
  float4* o4 = (float4*)out;
  float ls = 0.f;
  for (int f4 = tid; f4 < QB * 32; f4 += 512) {
    int ql = f4 >> 5;
    int d4 = f4 & 31;
    if (!flagmask[ql]) {
      size_t gi = (size_t)(q0 + ql) * 32 + d4;
      float4 xv = x4[gi];
      float4 wvv = w4[(size_t)bidx_sh[ql] * 32 + d4];
      float4 o;
      float t0 = wvv.x - xv.x; o.x = xv.x + t0; float e0 = o.x - xv.x;
      float t1 = wvv.y - xv.y; o.y = xv.y + t1; float e1 = o.y - xv.y;
      float t2 = wvv.z - xv.z; o.z = xv.z + t2; float e2 = o.z - xv.z;
      float t3 = wvv.w - xv.w; o.w = xv.w + t3; float e3 = o.w - xv.w;
      ls += e0 * e0 + e1 * e1 + e2 * e2 + e3 * e3;
      o4[gi] = o;
    }
  }
  for (int off = 32; off; off >>= 1) ls += __shfl_down(ls, off);
  if (lane == 0) lred[wv] = ls;
  __syncthreads();
  if (tid == 0) {
    float t = 0.f;
    for (int i = 0; i < 8; ++i) t += lred[i];
    part[blockIdx.x] = t;
  }
}

// ---------------------------------------------------------------------------
// Fixup: for flagged queries, emulate the reference's fp32 computation:
//   dist = fl32( fl32(l2q32 + l2k32[c]) - fl32(2 * fl32(q.k)) )
// q.k exact in fp64 then rounded once to fp32. First-index tie-break.
// Then performs the EPILOGUE for the corrected query (out/idx/counts/loss
// into part[512]) — these queries were skipped by argmin's fused epilogue.
// Grid 1024 (was 256): more parallelism across flagged queries.
// ---------------------------------------------------------------------------
__global__ __launch_bounds__(256) void fixup_kernel(const float* __restrict__ x,
                                                    const float* __restrict__ w,
                                                    const float* __restrict__ l2k32,
                                                    const int* __restrict__ flagged,
                                                    const int* __restrict__ flag_count,
                                                    int* __restrict__ best_idx,
                                                    float* __restrict__ out,
                                                    float* __restrict__ part,
                                                    int* __restrict__ counts) {
  __shared__ float qs[D_DIM];
  __shared__ float l2q_sh;
  __shared__ float redD[256];
  __shared__ int redI[256];
  const int tid = threadIdx.x;
  const int n = *flag_count;
  for (int f = blockIdx.x; f < n; f += gridDim.x) {
    __syncthreads();
    int q = flagged[f];
    if (tid < D_DIM) qs[tid] = x[(size_t)q * D_DIM + tid];
    __syncthreads();
    if (tid == 0) {
      double s = 0.0;
      for (int d = 0; d < D_DIM; ++d) {
        float t = qs[d] * qs[d];
        s += (double)t;
      }
      l2q_sh = (float)s;
    }
    __syncthreads();
    const float l2q = l2q_sh;
    float bd = 3.4e38f;
    int bi = 0x7fffffff;
    for (int c = tid; c < M_CODES; c += 256) {
      const float4* wr = (const float4*)(w + (size_t)c * D_DIM);
      double s = 0.0;
#pragma unroll
      for (int j = 0; j < 32; ++j) {
        float4 v = wr[j];
        s = fma((double)qs[j * 4 + 0], (double)v.x, s);
        s = fma((double)qs[j * 4 + 1], (double)v.y, s);
        s = fma((double)qs[j * 4 + 2], (double)v.z, s);
        s = fma((double)qs[j * 4 + 3], (double)v.w, s);
      }
      float simf = (float)s;
      float S = l2q + l2k32[c];
      float T = 2.0f * simf;
      float dist = S - T;
      if (dist < bd) { bd = dist; bi = c; }
    }
    redD[tid] = bd;
    redI[tid] = bi;
    __syncthreads();
    for (int off = 128; off; off >>= 1) {
      if (tid < off) {
        float od = redD[tid + off];
        int oi = redI[tid + off];
        if (od < redD[tid] || (od == redD[tid] && oi < redI[tid])) {
          redD[tid] = od;
          redI[tid] = oi;
        }
      }
      __syncthreads();
    }
    const int idx = redI[0];            // all threads read after the sync
    if (tid == 0) {
      best_idx[q] = idx;
      out[OUT_IDX + q] = (float)idx;
      atomicAdd(&counts[idx], 1);
    }
    // epilogue for this query: 32 float4 by lanes 0..31 of wave 0
    float lsq = 0.f;
    if (tid < 32) {
      size_t gi = (size_t)q * 32 + tid;
      float4 xv = ((const float4*)x)[gi];
      float4 wvv = ((const float4*)w)[(size_t)idx * 32 + tid];
      float4 o;
      float t0 = wvv.x - xv.x; o.x = xv.x + t0; float e0 = o.x - xv.x;
      float t1 = wvv.y - xv.y; o.y = xv.y + t1; float e1 = o.y - xv.y;
      float t2 = wvv.z - xv.z; o.z = xv.z + t2; float e2 = o.z - xv.z;
      float t3 = wvv.w - xv.w; o.w = xv.w + t3; float e3 = o.w - xv.w;
      lsq = e0 * e0 + e1 * e1 + e2 * e2 + e3 * e3;
      ((float4*)out)[gi] = o;
    }
    for (int off = 32; off; off >>= 1) lsq += __shfl_down(lsq, off);
    if (tid == 0) atomicAdd(&part[512], lsq);
  }
}

// ---------------------------------------------------------------------------
// Finalize: loss mean + perplexity. part[0..511] from argmin blocks,
// part[512] from fixup.
// ---------------------------------------------------------------------------
__global__ __launch_bounds__(256) void finalize_kernel(const int* __restrict__ counts,
                                                       const float* __restrict__ part,
                                                       float* __restrict__ out) {
  int tid = threadIdx.x;
  float ls = 0.f;
  for (int i = tid; i < 513; i += 256) ls += part[i];
  float es = 0.f;
  for (int i = tid; i < M_CODES; i += 256) {
    float p = (float)counts[i] * (1.0f / 65536.0f);
    es += p * logf(p + 1e-10f);
  }
  for (int off = 32; off; off >>= 1) {
    ls += __shfl_down(ls, off);
    es += __shfl_down(es, off);
  }
  __shared__ float redl[4], rede[4];
  if ((tid & 63) == 0) {
    redl[tid >> 6] = ls;
    rede[tid >> 6] = es;
  }
  __syncthreads();
  if (tid == 0) {
    out[OUT_LOSS] = (redl[0] + redl[1] + redl[2] + redl[3]) * (1.0f / 8388608.0f);
    out[OUT_PERP] = expf(-(rede[0] + rede[1] + rede[2] + rede[3]));
  }
}

extern "C" void kernel_launch(void* const* d_in, const int* in_sizes, int n_in,
                              void* d_out, int out_size, void* d_ws, size_t ws_size,
                              hipStream_t stream) {
  const float* x = (const float*)d_in[0];
  const float* w = (const float*)d_in[1];
  float* out = (float*)d_out;
  char* ws = (char*)d_ws;
  float* l2k = (float*)(ws + WS_L2K);
  __bf16* pb = (__bf16*)(ws + WS_PB);
  int* bidx = (int*)(ws + WS_IDX);
  float* part = (float*)(ws + WS_PART);
  int* counts = (int*)(ws + WS_CNT);
  int* flagcnt = (int*)(ws + WS_FLAGCNT);
  int* flagged = (int*)(ws + WS_FLAGGED);

  prep_kernel<<<256, 256, 0, stream>>>(w, l2k, pb, counts, flagcnt, part);
  argmin_mfma<<<BN_TOT / QB, 512, 0, stream>>>(x, pb, l2k, w, out, bidx,
                                               flagcnt, flagged, part, counts);
  fixup_kernel<<<1024, 256, 0, stream>>>(x, w, l2k, flagged, flagcnt, bidx,
                                         out, part, counts);
  finalize_kernel<<<1, 256, 0, stream>>>(counts, part, out);
}

// Round 13
// 227.610 us; speedup vs baseline: 5.1087x; 1.0087x over previous
//
#include <hip/hip_runtime.h>
#include <hip/hip_bf16.h>
#include <math.h>

// Problem constants
#define D_DIM 128
#define M_CODES 2048
#define BN_TOT 65536           // B*N = 16*4096
#define OUT_LOSS 8388608       // flat offset of loss
#define OUT_PERP 8388609       // flat offset of perp
#define OUT_IDX 8388610        // flat offset of indices
#define MARGIN 2e-3f           // covers ref fp32 noise (~1.6e-5) + bf16-split err

#define QB 128                 // queries per argmin block (4 q-groups x 2 slices)
#define FIX_BLOCKS 1024

// ws byte offsets
#define WS_L2K 0               // float l2k[2048]              (8 KB)
#define WS_PB 8192             // bf16 packed codebook, 1 MB: 64 pchunks x 16 KB
#define WS_IDX 1056768         // int best_idx[65536]          (256 KB)
#define WS_PART 1318912        // float loss_part[513 used]    (32 KB)
#define WS_CNT 1351680         // int counts[2048]             (8 KB)
#define WS_FLAGCNT 1359872     // int flag_count
#define WS_DONE 1359876        // int done counter (fixup last-block)
#define WS_FLAGGED 1360896     // int flagged[65536]           (256 KB)

typedef __bf16 bf16x8 __attribute__((ext_vector_type(8)));
typedef float f32x4 __attribute__((ext_vector_type(4)));

// async 16B/lane global->LDS copy: LDS dest is wave-uniform base + lane*16
#define GLOAD_LDS16(g, l)                                         \
  __builtin_amdgcn_global_load_lds(                               \
      (const __attribute__((address_space(1))) void*)(g),         \
      (__attribute__((address_space(3))) void*)(l), 16, 0, 0)

#define MFMA16(a, b, c) __builtin_amdgcn_mfma_f32_16x16x32_bf16((a), (b), (c), 0, 0, 0)

// ---------------------------------------------------------------------------
// prep: (a) emulated-np ||k||^2 (fp32-rounded terms, fp64 sum, round back),
// (b) codebook prepack, (c) counts / flag_count / done / part[512] zeroing.
// Pack layout (verified v3..v12): pchunk p (32 codes) = bytes
// [p*16384,(p+1)*16384); granule g = p*16 + cid; cid<8 hi (ks=cid>>1,
// wc=cid&1), cid>=8 lo; lane l: value = w[p*32+wc*16+(l&15)][ks*32+(l>>4)*8+j]
// ---------------------------------------------------------------------------
__global__ __launch_bounds__(256) void prep_kernel(const float* __restrict__ w,
                                                   float* __restrict__ l2k,
                                                   __bf16* __restrict__ pb,
                                                   int* __restrict__ counts,
                                                   int* __restrict__ flagcnt,
                                                   float* __restrict__ part,
                                                   int* __restrict__ done) {
  int gid = blockIdx.x * 256 + threadIdx.x;

  if (gid < M_CODES) {
    const float4* p = (const float4*)(w + (size_t)gid * D_DIM);
    double s = 0.0;
#pragma unroll
    for (int j = 0; j < 32; ++j) {
      float4 v = p[j];
      s += (double)(v.x * v.x);
      s += (double)(v.y * v.y);
      s += (double)(v.z * v.z);
      s += (double)(v.w * v.w);
    }
    l2k[gid] = (float)s;
    counts[gid] = 0;
    if (gid == 0) *flagcnt = 0;
    if (gid == 1) part[512] = 0.f;     // fixup loss slot
    if (gid == 2) *done = 0;
  }

  // pack: gid is a lane-granule id, 65536 total
  int lane = gid & 63;
  int g = gid >> 6;                          // granule 0..1023
  int cid = g & 15;
  int p = g >> 4;
  int k2 = cid & 7;
  int ks = k2 >> 1;
  int wc = k2 & 1;
  int code = p * 32 + wc * 16 + (lane & 15);
  int koff = ks * 32 + (lane >> 4) * 8;
  const float* src = w + (size_t)code * D_DIM + koff;
  float4 u = *(const float4*)src;
  float4 v = *(const float4*)(src + 4);
  float f[8] = {u.x, u.y, u.z, u.w, v.x, v.y, v.z, v.w};
  bf16x8 o;
#pragma unroll
  for (int j = 0; j < 8; ++j) {
    __bf16 hh = (__bf16)f[j];
    o[j] = (cid < 8) ? hh : (__bf16)(f[j] - (float)hh);
  }
  *(bf16x8*)(pb + (size_t)g * 512 + lane * 8) = o;
}

// max-form merge: (b,s)=best/second-best of acc (=sim-0.5*l2k; argmax),
// first-index tie-break
__device__ __forceinline__ void merge_bs(float& b, float& s, int& i,
                                         float ob, float os, int oi) {
  if (ob > b) {
    s = fmaxf(b, os);
    b = ob;
    i = oi;
  } else if (ob < b) {
    s = fmaxf(s, ob);
  } else {           // tie: gap 0 -> flagged -> fixup resolves exactly
    s = b;
    if (oi < i) i = oi;
  }
}

// ---------------------------------------------------------------------------
// MFMA argmin v13 = EXACT v12 (verified 117us, total 229.6us): v8/v11 main
// loop + fused block-local epilogue for unflagged queries. No fences.
// ---------------------------------------------------------------------------
__global__ __launch_bounds__(512, 4) void argmin_mfma(
    const float* __restrict__ x, const __bf16* __restrict__ pb,
    const float* __restrict__ l2k, const float* __restrict__ w,
    float* __restrict__ out, int* __restrict__ best_idx,
    int* __restrict__ flag_count, int* __restrict__ flagged,
    float* __restrict__ part, int* __restrict__ counts) {
  __shared__ __align__(16) unsigned char ldsB[2 * 32768];
  __shared__ float redB[8][32];
  __shared__ float redS[8][32];
  __shared__ int redI[8][32];
  __shared__ int flagmask[QB];
  __shared__ int bidx_sh[QB];
  __shared__ float lred[8];

  const int tid = threadIdx.x;
  const int wv = tid >> 6;        // wave 0..7
  const int lane = tid & 63;
  const int col = lane & 15;      // MFMA n-index / A m-index
  const int quad = lane >> 4;     // 0..3
  const int wc = wv & 1;          // code-slice within pchunk
  const int wq = wv >> 1;         // query group 0..3 (32 q each)
  const int q0 = blockIdx.x * QB;

  // ---- A fragments for this wave's 32 queries, fp32 -> hi/lo bf16, in regs
  bf16x8 ah[2][4], al[2][4];
#pragma unroll
  for (int mt = 0; mt < 2; ++mt) {
#pragma unroll
    for (int ks = 0; ks < 4; ++ks) {
      const float* xr =
          x + (size_t)(q0 + wq * 32 + 16 * mt + col) * D_DIM + 32 * ks + 8 * quad;
      float4 u = *(const float4*)xr;
      float4 v = *(const float4*)(xr + 4);
      float f[8] = {u.x, u.y, u.z, u.w, v.x, v.y, v.z, v.w};
      bf16x8 h, l;
#pragma unroll
      for (int j = 0; j < 8; ++j) {
        __bf16 hh = (__bf16)f[j];
        h[j] = hh;
        l[j] = (__bf16)(f[j] - (float)hh);
      }
      ah[mt][ks] = h;
      al[mt][ks] = l;
    }
  }

  // per-lane running argmax state over acc = sim - 0.5*l2k
  float m1[2][4], m2[2][4];
  int bp[2][4];                   // best pchunk id (full index rebuilt later)
#pragma unroll
  for (int mt = 0; mt < 2; ++mt)
#pragma unroll
    for (int r = 0; r < 4; ++r) {
      m1[mt][r] = -3.4e38f;
      m2[mt][r] = -3.4e38f;
      bp[mt][r] = 0;
    }

  const int ldsw = wc * 1024 + lane * 16;
  const float* l2p = l2k + wc * 16 + col;

  // stage chunk ch (64 codes = 32 KB = pchunks 2ch, 2ch+1); 4 granules/wave.
  // db MUST include the per-wave dest offset (+wv*4096) — v6 lesson.
  auto stage = [&](int ch, unsigned char* db) {
    const char* s = (const char*)pb + (size_t)ch * 32768 + wv * 4096 + lane * 16;
#pragma unroll
    for (int i = 0; i < 4; ++i) GLOAD_LDS16(s + i * 1024, db + i * 1024);
  };

  stage(0, ldsB + wv * 4096);     // per-wave dest offset!
  float l2a = l2p[0];
  float l2b = l2p[32];
  __syncthreads();   // drains vmcnt -> stage(0) complete

#pragma unroll 1
  for (int ch = 0; ch < 32; ++ch) {
    const int buf = ch & 1;
    if (ch < 31) stage(ch + 1, ldsB + (buf ^ 1) * 32768 + wv * 4096);
    float l2na = 0.f, l2nb = 0.f;
    if (ch < 31) {                          // l2 for chunk ch+1 (latency hidden)
      l2na = l2p[(2 * ch + 2) * 32];
      l2nb = l2p[(2 * ch + 3) * 32];
    }

    // ---- compute chunk ch: 48 MFMA, explicit 1-ks-ahead B prefetch ----
    const unsigned char* rb = ldsB + buf * 32768 + ldsw;
    float ia = -0.5f * l2a, ib = -0.5f * l2b;
    f32x4 a00 = (f32x4){ia, ia, ia, ia};
    f32x4 a10 = (f32x4){ia, ia, ia, ia};
    f32x4 a01 = (f32x4){ib, ib, ib, ib};
    f32x4 a11 = (f32x4){ib, ib, ib, ib};

    bf16x8 h0 = *(const bf16x8*)(rb);              // ks cur, nt0 hi
    bf16x8 l0 = *(const bf16x8*)(rb + 8192);       // ks cur, nt0 lo
    bf16x8 h1 = *(const bf16x8*)(rb + 16384);      // ks cur, nt1 hi
    bf16x8 l1 = *(const bf16x8*)(rb + 24576);      // ks cur, nt1 lo

#define DO_KS(KS, PRE)                                                    \
    {                                                                     \
      bf16x8 nh0, nl0, nh1, nl1;                                          \
      if (PRE) {                                                          \
        nh0 = *(const bf16x8*)(rb + ((KS) + 1) * 2048);                   \
        nl0 = *(const bf16x8*)(rb + 8192 + ((KS) + 1) * 2048);            \
        nh1 = *(const bf16x8*)(rb + 16384 + ((KS) + 1) * 2048);           \
        nl1 = *(const bf16x8*)(rb + 24576 + ((KS) + 1) * 2048);           \
      }                                                                   \
      a00 = MFMA16(al[0][KS], h0, a00);                                   \
      a10 = MFMA16(al[1][KS], h0, a10);                                   \
      a01 = MFMA16(al[0][KS], h1, a01);                                   \
      a11 = MFMA16(al[1][KS], h1, a11);                                   \
      a00 = MFMA16(ah[0][KS], l0, a00);                                   \
      a10 = MFMA16(ah[1][KS], l0, a10);                                   \
      a01 = MFMA16(ah[0][KS], l1, a01);                                   \
      a11 = MFMA16(ah[1][KS], l1, a11);                                   \
      a00 = MFMA16(ah[0][KS], h0, a00);                                   \
      a10 = MFMA16(ah[1][KS], h0, a10);                                   \
      a01 = MFMA16(ah[0][KS], h1, a01);                                   \
      a11 = MFMA16(ah[1][KS], h1, a11);                                   \
      if (PRE) { h0 = nh0; l0 = nl0; h1 = nh1; l1 = nl1; }                \
    }
    DO_KS(0, 1)
    DO_KS(1, 1)
    DO_KS(2, 1)
    DO_KS(3, 0)
#undef DO_KS

    // fold (argmax, branchless second-max, pchunk-id index).
    // candidates ascend over (ch, nt) -> strict > keeps first index.
#pragma unroll
    for (int mt = 0; mt < 2; ++mt) {
#pragma unroll
      for (int r = 0; r < 4; ++r) {
        float dd = (mt == 0) ? a00[r] : a10[r];
        bool gt = dd > m1[mt][r];
        m2[mt][r] = fmaxf(m2[mt][r], fminf(m1[mt][r], dd));
        bp[mt][r] = gt ? (ch * 2 + 0) : bp[mt][r];
        m1[mt][r] = fmaxf(m1[mt][r], dd);
      }
    }
#pragma unroll
    for (int mt = 0; mt < 2; ++mt) {
#pragma unroll
      for (int r = 0; r < 4; ++r) {
        float dd = (mt == 0) ? a01[r] : a11[r];
        bool gt = dd > m1[mt][r];
        m2[mt][r] = fmaxf(m2[mt][r], fminf(m1[mt][r], dd));
        bp[mt][r] = gt ? (ch * 2 + 1) : bp[mt][r];
        m1[mt][r] = fmaxf(m1[mt][r], dd);
      }
    }

    l2a = l2na;
    l2b = l2nb;
    __syncthreads();              // next buf staged + this buf reads done
  }

  // ---- Cross-lane reduction: 16 cols per quad-row ----
#pragma unroll
  for (int mt = 0; mt < 2; ++mt) {
#pragma unroll
    for (int r = 0; r < 4; ++r) {
      float b = m1[mt][r], s = m2[mt][r];
      int i = bp[mt][r] * 32 + wc * 16 + col;   // full code index
#pragma unroll
      for (int m = 1; m < 16; m <<= 1) {
        float ob = __shfl_xor(b, m);
        float os = __shfl_xor(s, m);
        int oi = __shfl_xor(i, m);
        merge_bs(b, s, i, ob, os, oi);
      }
      if (col == 0) {
        int qloc = 16 * mt + 4 * quad + r;
        redB[wv][qloc] = b;
        redS[wv][qloc] = s;
        redI[wv][qloc] = i;
      }
    }
  }
  __syncthreads();

  // ---- Final merge + flag decision (per query) ----
  if (tid < QB) {
    int wg = tid >> 5;            // query group 0..3
    int ql = tid & 31;
    float b = -3.4e38f, s = -3.4e38f;
    int i = 0x7fffffff;
    merge_bs(b, s, i, redB[wg * 2 + 0][ql], redS[wg * 2 + 0][ql], redI[wg * 2 + 0][ql]);
    merge_bs(b, s, i, redB[wg * 2 + 1][ql], redS[wg * 2 + 1][ql], redI[wg * 2 + 1][ql]);
    best_idx[q0 + tid] = i;
    bidx_sh[tid] = i;
    // dist gap = 2*(b - s) on acc scale
    int fl = (2.0f * (b - s) < MARGIN) ? 1 : 0;
    flagmask[tid] = fl;
    if (fl) {
      int pos = atomicAdd(flag_count, 1);
      flagged[pos] = q0 + tid;
    } else {
      out[OUT_IDX + q0 + tid] = (float)i;   // idx-out + histogram (q-level)
      atomicAdd(&counts[i], 1);
    }
  }
  __syncthreads();

  // ---- Fused epilogue for UNFLAGGED queries of this block ----
  // 128 q x 32 float4 = 4096 float4, 8 iters of 512 threads; coalesced.
  const float4* x4 = (const float4*)x;
  const float4* w4 = (const float4*)w;
  float4* o4 = (float4*)out;
  float ls = 0.f;
  for (int f4 = tid; f4 < QB * 32; f4 += 512) {
    int ql = f4 >> 5;
    int d4 = f4 & 31;
    if (!flagmask[ql]) {
      size_t gi = (size_t)(q0 + ql) * 32 + d4;
      float4 xv = x4[gi];
      float4 wvv = w4[(size_t)bidx_sh[ql] * 32 + d4];
      float4 o;
      float t0 = wvv.x - xv.x; o.x = xv.x + t0; float e0 = o.x - xv.x;
      float t1 = wvv.y - xv.y; o.y = xv.y + t1; float e1 = o.y - xv.y;
      float t2 = wvv.z - xv.z; o.z = xv.z + t2; float e2 = o.z - xv.z;
      float t3 = wvv.w - xv.w; o.w = xv.w + t3; float e3 = o.w - xv.w;
      ls += e0 * e0 + e1 * e1 + e2 * e2 + e3 * e3;
      o4[gi] = o;
    }
  }
  for (int off = 32; off; off >>= 1) ls += __shfl_down(ls, off);
  if (lane == 0) lred[wv] = ls;
  __syncthreads();
  if (tid == 0) {
    float t = 0.f;
    for (int i = 0; i < 8; ++i) t += lred[i];
    part[blockIdx.x] = t;
  }
}

// ---------------------------------------------------------------------------
// Fixup + FUSED FINALIZE (fence-free last-block pattern):
// For flagged queries: exact fp32-emulation rescan (q.k in fp64, rounded
// once) + the per-query epilogue (out/idx/counts/loss into part[512]).
// Then every block: s_waitcnt vmcnt(0) (drains OWN atomics — wave-local
// wait, NOT a cache fence) -> atomicAdd(done). Last block runs finalize,
// reading counts/part[512] via device-scope ATOMIC reads (atomicAdd(p,0))
// — coherent by construction, no __threadfence anywhere (v9 lesson:
// per-block device fences cost ~600us). part[0..511] is from the previous
// kernel -> visible via stream order.
// ---------------------------------------------------------------------------
__global__ __launch_bounds__(256) void fixup_kernel(const float* __restrict__ x,
                                                    const float* __restrict__ w,
                                                    const float* __restrict__ l2k32,
                                                    const int* __restrict__ flagged,
                                                    const int* __restrict__ flag_count,
                                                    int* __restrict__ best_idx,
                                                    float* __restrict__ out,
                                                    float* __restrict__ part,
                                                    int* __restrict__ counts,
                                                    int* __restrict__ done) {
  __shared__ float qs[D_DIM];
  __shared__ float l2q_sh;
  __shared__ float redD[256];
  __shared__ int redI[256];
  __shared__ int amlast;
  const int tid = threadIdx.x;
  const int n = *flag_count;
  for (int f = blockIdx.x; f < n; f += gridDim.x) {
    __syncthreads();
    int q = flagged[f];
    if (tid < D_DIM) qs[tid] = x[(size_t)q * D_DIM + tid];
    __syncthreads();
    if (tid == 0) {
      double s = 0.0;
      for (int d = 0; d < D_DIM; ++d) {
        float t = qs[d] * qs[d];
        s += (double)t;
      }
      l2q_sh = (float)s;
    }
    __syncthreads();
    const float l2q = l2q_sh;
    float bd = 3.4e38f;
    int bi = 0x7fffffff;
    for (int c = tid; c < M_CODES; c += 256) {
      const float4* wr = (const float4*)(w + (size_t)c * D_DIM);
      double s = 0.0;
#pragma unroll
      for (int j = 0; j < 32; ++j) {
        float4 v = wr[j];
        s = fma((double)qs[j * 4 + 0], (double)v.x, s);
        s = fma((double)qs[j * 4 + 1], (double)v.y, s);
        s = fma((double)qs[j * 4 + 2], (double)v.z, s);
        s = fma((double)qs[j * 4 + 3], (double)v.w, s);
      }
      float simf = (float)s;
      float S = l2q + l2k32[c];
      float T = 2.0f * simf;
      float dist = S - T;
      if (dist < bd) { bd = dist; bi = c; }
    }
    redD[tid] = bd;
    redI[tid] = bi;
    __syncthreads();
    for (int off = 128; off; off >>= 1) {
      if (tid < off) {
        float od = redD[tid + off];
        int oi = redI[tid + off];
        if (od < redD[tid] || (od == redD[tid] && oi < redI[tid])) {
          redD[tid] = od;
          redI[tid] = oi;
        }
      }
      __syncthreads();
    }
    const int idx = redI[0];            // all threads read after the sync
    if (tid == 0) {
      best_idx[q] = idx;
      out[OUT_IDX + q] = (float)idx;
      atomicAdd(&counts[idx], 1);
    }
    // epilogue for this query: 32 float4 by lanes 0..31 of wave 0
    float lsq = 0.f;
    if (tid < 32) {
      size_t gi = (size_t)q * 32 + tid;
      float4 xv = ((const float4*)x)[gi];
      float4 wvv = ((const float4*)w)[(size_t)idx * 32 + tid];
      float4 o;
      float t0 = wvv.x - xv.x; o.x = xv.x + t0; float e0 = o.x - xv.x;
      float t1 = wvv.y - xv.y; o.y = xv.y + t1; float e1 = o.y - xv.y;
      float t2 = wvv.z - xv.z; o.z = xv.z + t2; float e2 = o.z - xv.z;
      float t3 = wvv.w - xv.w; o.w = xv.w + t3; float e3 = o.w - xv.w;
      lsq = e0 * e0 + e1 * e1 + e2 * e2 + e3 * e3;
      ((float4*)out)[gi] = o;
    }
    for (int off = 32; off; off >>= 1) lsq += __shfl_down(lsq, off);
    if (tid == 0) atomicAdd(&part[512], lsq);
  }

  // ---- last-block finalize (fence-free) ----
  __syncthreads();
  // drain this wave's outstanding VMEM ops (stores + atomics) so they have
  // reached the coherent point before we announce completion. Wave-local
  // wait — cheap, not an L2 writeback fence.
  asm volatile("s_waitcnt vmcnt(0)" ::: "memory");
  if (tid == 0) amlast = (atomicAdd(done, 1) == FIX_BLOCKS - 1) ? 1 : 0;
  __syncthreads();
  if (!amlast) return;

  // All 1023 other blocks have completed their atomics (vmcnt-drained
  // before their done-increment). Read shared state via atomic reads.
  float ls = 0.f;
  for (int i = tid; i < 512; i += 256) ls += part[i];      // argmin kernel: stream-ordered
  if (tid == 0) ls += atomicAdd(&part[512], 0.0f);         // fixup blocks: atomic read
  float es = 0.f;
  for (int i = tid; i < M_CODES; i += 256) {
    int c = atomicAdd(&counts[i], 0);                      // atomic read
    float p = (float)c * (1.0f / 65536.0f);
    es += p * logf(p + 1e-10f);
  }
  for (int off = 32; off; off >>= 1) {
    ls += __shfl_down(ls, off);
    es += __shfl_down(es, off);
  }
  __shared__ float redl[4], rede[4];
  if ((tid & 63) == 0) {
    redl[tid >> 6] = ls;
    rede[tid >> 6] = es;
  }
  __syncthreads();
  if (tid == 0) {
    out[OUT_LOSS] = (redl[0] + redl[1] + redl[2] + redl[3]) * (1.0f / 8388608.0f);
    out[OUT_PERP] = expf(-(rede[0] + rede[1] + rede[2] + rede[3]));
  }
}

extern "C" void kernel_launch(void* const* d_in, const int* in_sizes, int n_in,
                              void* d_out, int out_size, void* d_ws, size_t ws_size,
                              hipStream_t stream) {
  const float* x = (const float*)d_in[0];
  const float* w = (const float*)d_in[1];
  float* out = (float*)d_out;
  char* ws = (char*)d_ws;
  float* l2k = (float*)(ws + WS_L2K);
  __bf16* pb = (__bf16*)(ws + WS_PB);
  int* bidx = (int*)(ws + WS_IDX);
  float* part = (float*)(ws + WS_PART);
  int* counts = (int*)(ws + WS_CNT);
  int* flagcnt = (int*)(ws + WS_FLAGCNT);
  int* done = (int*)(ws + WS_DONE);
  int* flagged = (int*)(ws + WS_FLAGGED);

  prep_kernel<<<256, 256, 0, stream>>>(w, l2k, pb, counts, flagcnt, part, done);
  argmin_mfma<<<BN_TOT / QB, 512, 0, stream>>>(x, pb, l2k, w, out, bidx,
                                               flagcnt, flagged, part, counts);
  fixup_kernel<<<FIX_BLOCKS, 256, 0, stream>>>(x, w, l2k, flagged, flagcnt, bidx,
                                               out, part, counts, done);
}